// Round 14
// baseline (244.528 us; speedup 1.0000x reference)
//
#include <hip/hip_runtime.h>

#define DM    2048
#define NH    16
#define HD    128
#define TSEQ  2048
#define BATCH 2
#define MROWS (BATCH * TSEQ)   // 4096

typedef __bf16 bf16_t;
typedef __bf16 bf16x8 __attribute__((ext_vector_type(8)));
typedef __bf16 bf16x4 __attribute__((ext_vector_type(4)));
typedef float  f32x4  __attribute__((ext_vector_type(4)));
typedef float  f32x16 __attribute__((ext_vector_type(16)));
typedef unsigned short u16x8 __attribute__((ext_vector_type(8)));
typedef unsigned int   u32;

static __device__ __forceinline__ unsigned short f2bf_bits(float f) {
  unsigned u = __builtin_bit_cast(unsigned, f);
  u += 0x7fffu + ((u >> 16) & 1u);            // round-to-nearest-even
  return (unsigned short)(u >> 16);
}
static __device__ __forceinline__ bf16_t f2bf(float f) {
  unsigned short h = f2bf_bits(f);
  return __builtin_bit_cast(bf16_t, h);
}

static __device__ __forceinline__ void gll16(const void* g, void* lds) {
  __builtin_amdgcn_global_load_lds(
      (const __attribute__((address_space(1))) unsigned int*)g,
      (__attribute__((address_space(3))) unsigned int*)lds, 16, 0, 0);
}

static __device__ __forceinline__ float fast_exp2(float x) {
#if __has_builtin(__builtin_amdgcn_exp2f)
  return __builtin_amdgcn_exp2f(x);
#else
  return exp2f(x);
#endif
}
static __device__ __forceinline__ float fast_rcp(float x) {
#if __has_builtin(__builtin_amdgcn_rcpf)
  return __builtin_amdgcn_rcpf(x);
#else
  return 1.0f / x;
#endif
}

// v_cvt_pk_bf16_f32: dst.lo16 = bf16(a), dst.hi16 = bf16(b)
static __device__ __forceinline__ u32 cvtpk(float a, float b) {
  u32 d;
  asm("v_cvt_pk_bf16_f32 %0, %1, %2" : "=v"(d) : "v"(a), "v"(b));
  return d;
}
// v_permlane32_swap_b32 a, b: a.hi32lanes <-> b.lo32lanes
static __device__ __forceinline__ void pl32swap(u32& a, u32& b) {
  asm volatile("v_permlane32_swap_b32 %0, %1" : "+v"(a), "+v"(b));
}

// ---------------- fused fp32 -> bf16 convert: x + 4 weights, ONE dispatch ------
__global__ void cvt_all(const float* __restrict__ x,
                        const float* __restrict__ w0, const float* __restrict__ w1,
                        const float* __restrict__ w2, const float* __restrict__ w3,
                        bf16_t* __restrict__ dx, bf16_t* __restrict__ dw,
                        int nx8, int nw8) {
  const int i = blockIdx.x * blockDim.x + threadIdx.x;
  const float* s;
  bf16_t* d;
  int j;
  if (i < nx8) {
    s = x; d = dx; j = i;
  } else {
    const int k = i - nx8;
    const int seg = k / nw8;
    j = k - seg * nw8;
    s = (seg == 0) ? w0 : (seg == 1) ? w1 : (seg == 2) ? w2 : w3;
    d = dw + (size_t)seg * DM * DM;
  }
  const float4* sp = reinterpret_cast<const float4*>(s);
  float4 a = sp[2 * j], b = sp[2 * j + 1];
  u16x8 o;
  o[0] = f2bf_bits(a.x); o[1] = f2bf_bits(a.y); o[2] = f2bf_bits(a.z); o[3] = f2bf_bits(a.w);
  o[4] = f2bf_bits(b.x); o[5] = f2bf_bits(b.y); o[6] = f2bf_bits(b.z); o[7] = f2bf_bits(b.w);
  reinterpret_cast<u16x8*>(d)[j] = o;
}

// ---------------- 3-buffer counted-vmcnt GEMM: C[M,N] = A[M,K] * B[N,K]^T ------
// BM=256, BN=128, BK=64, 512 thr = 8 waves (4M x 2N), per-wave 64x64.
// Round-8 config + stage-after-MFMA reorder: MFMAs issue immediately after the
// ds_reads (no stage-issue VALU in between); the 6 gll16 issues land right
// before vmcnt(6), preserving the counted semantics exactly.
template <int OUTM>
__global__ __launch_bounds__(512, 1) void gemm_3buf(
    const bf16_t* __restrict__ A, const bf16_t* __restrict__ B,
    void* __restrict__ Cq, void* __restrict__ Ck, void* __restrict__ Cv) {
  __shared__ bf16_t Asm[3][256 * 64];   // 96 KB
  __shared__ bf16_t Bsm[3][128 * 64];   // 48 KB
  const int tid = threadIdx.x;
  const int l = tid & 63, w = tid >> 6;
  const int wm = w >> 1, wn = w & 1;
  const int m0 = blockIdx.y * 256, n0 = blockIdx.x * 128;
  const int NT = DM / 64;   // 32

  auto SA = [&](int t, int buf, int s) {          // s = 0..3 (A: 256 rows)
    const int rowbase = s * 64 + w * 8;           // wave-uniform
    const int row = rowbase + (l >> 3);
    const int ug = (l & 7) ^ (row & 7);
    const int tc = (t < NT) ? t : 0;              // dummy clamp (keeps vmcnt uniform)
    gll16(A + (size_t)(m0 + row) * DM + tc * 64 + ug * 8,
          (char*)Asm[buf] + rowbase * 128);
  };
  auto SB = [&](int t, int buf, int s) {          // s = 0..1 (B: 128 rows)
    const int rowbase = s * 64 + w * 8;
    const int row = rowbase + (l >> 3);
    const int ug = (l & 7) ^ (row & 7);
    const int tc = (t < NT) ? t : 0;
    gll16(B + (size_t)(n0 + row) * DM + tc * 64 + ug * 8,
          (char*)Bsm[buf] + rowbase * 128);
  };

  f32x4 acc[4][4] = {};

  // Prologue: stage tiles 0 and 1 (6 loads each).
#pragma unroll
  for (int s = 0; s < 4; ++s) SA(0, 0, s);
  SB(0, 0, 0); SB(0, 0, 1);
#pragma unroll
  for (int s = 0; s < 4; ++s) SA(1, 1, s);
  SB(1, 1, 0); SB(1, 1, 1);
  asm volatile("s_waitcnt vmcnt(6)" ::: "memory");   // tile 0 complete
  __builtin_amdgcn_s_barrier();
  __builtin_amdgcn_sched_barrier(0);

  for (int j = 0; j < NT; ++j) {
    const int bj = j % 3, bs = (j + 2) % 3;
    const char* Ab_ = (const char*)Asm[bj];
    const char* Bb_ = (const char*)Bsm[bj];
    bf16x8 af[4][2], bfr[4][2];

    // ---- full-tile ds_read burst (16 x b128, swizzled) ----
#pragma unroll
    for (int mi = 0; mi < 4; ++mi)
#pragma unroll
      for (int kh = 0; kh < 2; ++kh) {
        const int row = wm * 64 + mi * 16 + (l & 15);
        const int u = (kh * 4 + (l >> 4)) ^ (row & 7);
        af[mi][kh] = *reinterpret_cast<const bf16x8*>(Ab_ + row * 128 + u * 16);
      }
#pragma unroll
    for (int ni = 0; ni < 4; ++ni)
#pragma unroll
      for (int kh = 0; kh < 2; ++kh) {
        const int row = wn * 64 + ni * 16 + (l & 15);
        const int u = (kh * 4 + (l >> 4)) ^ (row & 7);
        bfr[ni][kh] = *reinterpret_cast<const bf16x8*>(Bb_ + row * 128 + u * 16);
      }

    // ---- 32 MFMA immediately (compiler interleaves via counted lgkmcnt) ----
    __builtin_amdgcn_s_setprio(1);
#pragma unroll
    for (int kh = 0; kh < 2; ++kh)
#pragma unroll
      for (int mi = 0; mi < 4; ++mi)
#pragma unroll
        for (int ni = 0; ni < 4; ++ni)
          acc[mi][ni] = __builtin_amdgcn_mfma_f32_16x16x32_bf16(
              af[mi][kh], bfr[ni][kh], acc[mi][ni], 0, 0, 0);
    __builtin_amdgcn_s_setprio(0);
    __builtin_amdgcn_sched_barrier(0);   // keep stage-issues below the MFMAs

    // ---- stage tile j+2 (6 x gll16), then counted drain ----
    SA(j + 2, bs, 0); SA(j + 2, bs, 1); SA(j + 2, bs, 2); SA(j + 2, bs, 3);
    SB(j + 2, bs, 0); SB(j + 2, bs, 1);
    asm volatile("s_waitcnt vmcnt(6)" ::: "memory");
    __builtin_amdgcn_s_barrier();
    __builtin_amdgcn_sched_barrier(0);
  }

  // ---- epilogue ----
  if constexpr (OUTM == 0) {
    const int proj = n0 >> 11;          // 0=Q, 1=K, 2=V (uniform per WG)
    const int nc0 = n0 & (DM - 1);
    if (proj < 2) {
      bf16_t* C = (bf16_t*)(proj == 0 ? Cq : Ck);
#pragma unroll
      for (int mi = 0; mi < 4; ++mi) {
        const int row = m0 + wm * 64 + mi * 16 + ((l >> 4) << 2);
#pragma unroll
        for (int ni = 0; ni < 4; ++ni) {
          const int col = nc0 + wn * 64 + ni * 16 + (l & 15);
#pragma unroll
          for (int r = 0; r < 4; ++r)
            C[(size_t)(row + r) * DM + col] = f2bf(acc[mi][ni][r]);
        }
      }
    } else {
      bf16_t* VT = (bf16_t*)Cv;
#pragma unroll
      for (int mi = 0; mi < 4; ++mi) {
        const int row = m0 + wm * 64 + mi * 16 + ((l >> 4) << 2);
        const int bb = row >> 11, tt = row & (TSEQ - 1);
#pragma unroll
        for (int ni = 0; ni < 4; ++ni) {
          const int col = nc0 + wn * 64 + ni * 16 + (l & 15);
          const int hh = col >> 7, dd = col & (HD - 1);
          bf16x4 pk;
#pragma unroll
          for (int r = 0; r < 4; ++r) pk[r] = f2bf(acc[mi][ni][r]);
          *reinterpret_cast<bf16x4*>(VT + (((size_t)bb * NH + hh) * HD + dd) * TSEQ + tt) = pk;
        }
      }
    }
  } else {
    float* C = (float*)Cq;
#pragma unroll
    for (int mi = 0; mi < 4; ++mi) {
      const int row = m0 + wm * 64 + mi * 16 + ((l >> 4) << 2);
#pragma unroll
      for (int ni = 0; ni < 4; ++ni) {
        const int col = n0 + wn * 64 + ni * 16 + (l & 15);
#pragma unroll
        for (int r = 0; r < 4; ++r)
          C[(size_t)(row + r) * DM + col] = acc[mi][ni][r];
      }
    }
  }
}

// ---------------- causal flash attention v7: 2 blocks/CU --------------------
// grid: (16, B*H) = 512 blocks of 256 thr = 4 waves (2 qw x 2 kw), 2 blocks/CU.
// 32 q-subtiles of 64 rows; block x runs subtile x (x+1 k-tiles) then subtile
// 31-x (32-x k-tiles): 33 tiles each, all blocks equal. Cross-block overlap
// fills barrier/drain stalls. Per-wave math identical to v6 (kv-split halves,
// in-register softmax, pair merge).
#define LDS_TOT 70656
__global__ __launch_bounds__(256, 2) void flash_attn(
    const bf16_t* __restrict__ Q, const bf16_t* __restrict__ Kx,
    const bf16_t* __restrict__ VT, bf16_t* __restrict__ O) {
  __shared__ __align__(16) char Lds[LDS_TOT];
  // staging (during loop): Ks[2] @0 (2x16 KB), Vs[2] @32768 (2x16 KB)
  // merge (after loop):   accbuf @0 (32 KB), ml @65536 (2 KB), ml2 @67584 (3 KB)

  const int tid = threadIdx.x;
  const int l = tid & 63, w = tid >> 6;        // 4 waves
  const int hi = l >> 5, ln31 = l & 31;
  const int qw = w >> 1, kw = w & 1;           // qw,kw in {0,1}
  const int bh = blockIdx.y;
  const int b = bh >> 4, h = bh & 15;
  const size_t base   = ((size_t)b * TSEQ) * DM + (size_t)h * HD;   // Q/K/O
  const size_t vtbase = ((size_t)b * NH + h) * HD * (size_t)TSEQ;   // V^T
  const float cc = 0.12752775f;  // (1/sqrt(128)) * log2(e)

  auto run_qtile = [&](int p) {                // p = 64-row subtile index, 0..31
    const int wq0 = p * 64 + qw * 32;
    const int nt = p + 1;

    // Q as B-operand: lane holds col q = ln31, k(d) = m*16 + hi*8 + j
    bf16x8 qf[8];
    {
      const bf16_t* qp = Q + base + (size_t)(wq0 + ln31) * DM + hi * 8;
#pragma unroll
      for (int m = 0; m < 8; ++m)
        qf[m] = *reinterpret_cast<const bf16x8*>(qp + m * 16);
    }

    f32x16 acc[4] = {};   // O_half: row q=crow(r,hi), col d = n*32 + ln31
    float mrow = -1e30f, lrow = 0.f;

    auto STAGE = [&](int t, int buf) {         // 4 waves x 4 chunks = 16 chunks
#pragma unroll
      for (int c = 0; c < 4; ++c) {
        const int chunk = w * 4 + c;                   // 0..15
        const int krow = chunk * 4 + (l >> 4);
        const int u = l & 15;
        const int ug = (u & 8) | ((u ^ krow) & 7);
        gll16(Kx + base + (size_t)(t * 64 + krow) * DM + ug * 8,
              Lds + buf * 16384 + chunk * 1024);
      }
#pragma unroll
      for (int c = 0; c < 4; ++c) {
        const int ci = w * 4 + c;                      // 0..15
        const int d = ci * 8 + (l >> 3);
        const int ug = (l & 7) ^ (l >> 3);
        gll16(VT + vtbase + (size_t)d * TSEQ + t * 64 + ug * 8,
              Lds + 32768 + buf * 16384 + ci * 1024);
      }
    };

    STAGE(0, 0);
    __syncthreads();
    int cur = 0;

    for (int t = 0; t < nt; ++t) {
      if (t + 1 < nt) STAGE(t + 1, cur ^ 1);

      const bool active = (t * 64 + kw * 32 <= wq0 + 31);
      if (active) {
        // ---- S^T_half = K_half Q^T : 8 MFMA ----
        f32x16 s = {};
        const char* Kb_ = Lds + cur * 16384;
        const int kvr = kw * 32 + ln31;
#pragma unroll
        for (int m = 0; m < 8; ++m) {
          const int u = 2 * m + hi;
          const int uswz = (u & 8) | ((u ^ kvr) & 7);
          const bf16x8 kf = *reinterpret_cast<const bf16x8*>(Kb_ + kvr * 256 + uswz * 16);
          s = __builtin_amdgcn_mfma_f32_32x32x16_bf16(kf, qf[m], s, 0, 0, 0);
        }

        // ---- scale + causal mask (q = ln31, kv = t*64 + kw*32 + crow(r,hi)) ----
        float sv[16];
        const int qg = wq0 + ln31;
#pragma unroll
        for (int r = 0; r < 16; ++r) sv[r] = s[r] * cc;
        if (t * 64 + kw * 32 + 31 > wq0) {
#pragma unroll
          for (int r = 0; r < 16; ++r) {
            const int kvg = t * 64 + kw * 32 + (r & 3) + 8 * (r >> 2) + 4 * hi;
            if (kvg > qg) sv[r] = -3.0e38f;
          }
        }

        // ---- row max over this half (16 regs + cross-hi) ----
        float mt = sv[0];
#pragma unroll
        for (int r = 1; r < 16; ++r) mt = fmaxf(mt, sv[r]);
        mt = fmaxf(mt, __shfl_xor(mt, 32, 64));

        // T13 defer-max; redistribute scl q->crow via shfl
        if (__any(mt > mrow + 8.0f)) {
          const float mn = fmaxf(mrow, mt);
          const float scl = fast_exp2(mrow - mn);
          mrow = mn;
          lrow *= scl;
#pragma unroll
          for (int r = 0; r < 16; ++r) {
            const float sr = __shfl(scl, (r & 3) + 8 * (r >> 2) + 4 * hi, 64);
            acc[0][r] *= sr; acc[1][r] *= sr; acc[2][r] *= sr; acc[3][r] *= sr;
          }
        }

        // ---- P = exp2(S - m), row sum ----
        float rs = 0.f;
#pragma unroll
        for (int r = 0; r < 16; ++r) {
          const float p2 = fast_exp2(sv[r] - mrow);
          sv[r] = p2;
          rs += p2;
        }
        rs += __shfl_xor(rs, 32, 64);
        lrow += rs;

        // ---- cvt_pk + permlane32_swap: 2 PV A-frags (kv-slots kw*2, kw*2+1) ----
        u32 frag[2][4];
#pragma unroll
        for (int f = 0; f < 2; ++f) {
          const float* pp = &sv[f * 8];
          u32 a1 = cvtpk(pp[0], pp[1]);
          u32 b1 = cvtpk(pp[4], pp[5]);
          pl32swap(a1, b1);
          u32 a2 = cvtpk(pp[2], pp[3]);
          u32 b2 = cvtpk(pp[6], pp[7]);
          pl32swap(a2, b2);
          frag[f][0] = a1; frag[f][1] = a2; frag[f][2] = b1; frag[f][3] = b2;
        }

        // ---- O_half += P_half V_half : 2 kv-slots x 4 d-tiles ----
        const char* Vb_ = Lds + 32768 + cur * 16384;
#pragma unroll
        for (int f = 0; f < 2; ++f) {
          const bf16x8 pf = __builtin_bit_cast(bf16x8, *reinterpret_cast<u32(*)[4]>(frag[f]));
#pragma unroll
          for (int n = 0; n < 4; ++n) {
            const int d = n * 32 + ln31;
            const int u = (kw * 2 + f) * 2 + hi;
            const int uswz = u ^ (d & 7);
            const bf16x8 vf = *reinterpret_cast<const bf16x8*>(Vb_ + d * 128 + uswz * 16);
            acc[n] = __builtin_amdgcn_mfma_f32_32x32x16_bf16(pf, vf, acc[n], 0, 0, 0);
          }
        }
      }
      __syncthreads();
      cur ^= 1;
    }

    // ---- kv-pair merge + store (split by d-halves) ----
    {
      // 1) write my NON-finalized accs: kw=0 writes acc[2],acc[3]; kw=1 acc[0],acc[1]
      float* accb = (float*)(Lds + qw * 16384 + kw * 8192);
      const int nb = (kw == 0) ? 2 : 0;
#pragma unroll
      for (int np = 0; np < 2; ++np) {
        float* dst = accb + np * 1024;
#pragma unroll
        for (int r = 0; r < 16; ++r) {
          const int row = (r & 3) + 8 * (r >> 2) + 4 * hi;
          dst[row * 32 + ln31] = acc[nb + np][r];
        }
      }
      float* mlp = (float*)(Lds + 65536 + qw * 1024 + kw * 512);
      if (hi == 0) { mlp[ln31] = mrow; mlp[32 + ln31] = lrow; }
      __syncthreads();

      // 2) merge scalars at lane = q
      const float* mlo = (float*)(Lds + 65536 + qw * 1024 + (kw ^ 1) * 512);
      const float mo = mlo[ln31], lo = mlo[32 + ln31];
      const float mm = fmaxf(mrow, mo);
      const float as = fast_exp2(mrow - mm);
      const float ao = fast_exp2(mo - mm);
      const float rln = fast_rcp(lrow * as + lo * ao);
      float* ml2p = (float*)(Lds + 67584 + qw * 1536 + kw * 768);
      if (hi == 0) { ml2p[ln31] = as; ml2p[32 + ln31] = ao; ml2p[64 + ln31] = rln; }
      __syncthreads();

      // 3) finalize my d-half: kw=0 -> d 0..63 (acc[0],acc[1]), kw=1 -> d 64..127
      const float* accoth = (float*)(Lds + qw * 16384 + (kw ^ 1) * 8192);
      const int nf = (kw == 0) ? 0 : 2;
#pragma unroll
      for (int r = 0; r < 16; ++r) {
        const int row = (r & 3) + 8 * (r >> 2) + 4 * hi;
        const float asr = ml2p[row];
        const float aor = ml2p[32 + row];
        const float rlr = ml2p[64 + row];
        const int q = wq0 + row;
        bf16_t* op = O + base + (size_t)q * DM + ln31;
#pragma unroll
        for (int np = 0; np < 2; ++np) {
          const float vo = (acc[nf + np][r] * asr + accoth[np * 1024 + row * 32 + ln31] * aor) * rlr;
          op[(kw * 2 + np) * 32] = f2bf(vo);
        }
      }
      __syncthreads();   // LDS safe for next leg's staging
    }
  };

  const int i = blockIdx.x;    // 0..15
  run_qtile(i);                // short leg: i+1 k-tiles
  run_qtile(31 - i);           // long leg: 32-i k-tiles (total 33)
}

// ---------------- launch ----------------
extern "C" void kernel_launch(void* const* d_in, const int* in_sizes, int n_in,
                              void* d_out, int out_size, void* d_ws, size_t ws_size,
                              hipStream_t stream) {
  (void)in_sizes; (void)n_in; (void)out_size; (void)ws_size;
  const float* x  = (const float*)d_in[0];
  const float* wq = (const float*)d_in[1];
  const float* wk = (const float*)d_in[2];
  const float* wv = (const float*)d_in[3];
  const float* wo = (const float*)d_in[4];
  float* out = (float*)d_out;

  const size_t nx = (size_t)MROWS * DM;  // 8388608
  const size_t nw = (size_t)DM * DM;     // 4194304
  bf16_t* xb  = (bf16_t*)d_ws;
  bf16_t* wqb = xb + nx;                 // wq/wk/wv/wo contiguous bf16
  bf16_t* Qb  = wqb + 4 * nw;
  bf16_t* Kb  = Qb + nx;
  bf16_t* Vtb = Kb + nx;   // V^T [B][H][d][t]
  bf16_t* Ab  = Vtb + nx;
  bf16_t* wob = wqb + 3 * nw;

  const int nx8 = (int)(nx / 8);         // 1048576
  const int nw8 = (int)(nw / 8);         // 524288
  const int ntot = nx8 + 4 * nw8;        // 3145728
  cvt_all<<<ntot / 256, 256, 0, stream>>>(x, wq, wk, wv, wo, xb, wqb, nx8, nw8);

  // fused QKV: B rows 0..2047 -> Q, 2048..4095 -> K, 4096..6143 -> V(T)
  gemm_3buf<0><<<dim3(3 * DM / 128, MROWS / 256), 512, 0, stream>>>(
      xb, wqb, Qb, Kb, Vtb);

  flash_attn<<<dim3(16, BATCH * NH), 256, 0, stream>>>(Qb, Kb, Vtb, Ab);

  gemm_3buf<1><<<dim3(DM / 128, MROWS / 256), 512, 0, stream>>>(
      Ab, wob, out, nullptr, nullptr);
}

// Round 15
// 221.524 us; speedup vs baseline: 1.1038x; 1.1038x over previous
//
#include <hip/hip_runtime.h>

#define DM    2048
#define NH    16
#define HD    128
#define TSEQ  2048
#define BATCH 2
#define MROWS (BATCH * TSEQ)   // 4096

typedef __bf16 bf16_t;
typedef __bf16 bf16x8 __attribute__((ext_vector_type(8)));
typedef __bf16 bf16x4 __attribute__((ext_vector_type(4)));
typedef float  f32x4  __attribute__((ext_vector_type(4)));
typedef float  f32x16 __attribute__((ext_vector_type(16)));
typedef unsigned short u16x8 __attribute__((ext_vector_type(8)));
typedef unsigned int   u32;

static __device__ __forceinline__ unsigned short f2bf_bits(float f) {
  unsigned u = __builtin_bit_cast(unsigned, f);
  u += 0x7fffu + ((u >> 16) & 1u);            // round-to-nearest-even
  return (unsigned short)(u >> 16);
}
static __device__ __forceinline__ bf16_t f2bf(float f) {
  unsigned short h = f2bf_bits(f);
  return __builtin_bit_cast(bf16_t, h);
}

static __device__ __forceinline__ void gll16(const void* g, void* lds) {
  __builtin_amdgcn_global_load_lds(
      (const __attribute__((address_space(1))) unsigned int*)g,
      (__attribute__((address_space(3))) unsigned int*)lds, 16, 0, 0);
}

static __device__ __forceinline__ float fast_exp2(float x) {
#if __has_builtin(__builtin_amdgcn_exp2f)
  return __builtin_amdgcn_exp2f(x);
#else
  return exp2f(x);
#endif
}
static __device__ __forceinline__ float fast_rcp(float x) {
#if __has_builtin(__builtin_amdgcn_rcpf)
  return __builtin_amdgcn_rcpf(x);
#else
  return 1.0f / x;
#endif
}

// v_cvt_pk_bf16_f32: dst.lo16 = bf16(a), dst.hi16 = bf16(b)
static __device__ __forceinline__ u32 cvtpk(float a, float b) {
  u32 d;
  asm("v_cvt_pk_bf16_f32 %0, %1, %2" : "=v"(d) : "v"(a), "v"(b));
  return d;
}
// v_permlane32_swap_b32 a, b: a.hi32lanes <-> b.lo32lanes
static __device__ __forceinline__ void pl32swap(u32& a, u32& b) {
  asm volatile("v_permlane32_swap_b32 %0, %1" : "+v"(a), "+v"(b));
}

// ---------------- fused fp32 -> bf16 convert: x + 4 weights, ONE dispatch ------
// item i = 8 elements. Items: [0, nx8) -> x; then 4 segments of nw8 -> weights.
__global__ void cvt_all(const float* __restrict__ x,
                        const float* __restrict__ w0, const float* __restrict__ w1,
                        const float* __restrict__ w2, const float* __restrict__ w3,
                        bf16_t* __restrict__ dx, bf16_t* __restrict__ dw,
                        int nx8, int nw8) {
  const int i = blockIdx.x * blockDim.x + threadIdx.x;
  const float* s;
  bf16_t* d;
  int j;
  if (i < nx8) {
    s = x; d = dx; j = i;
  } else {
    const int k = i - nx8;
    const int seg = k / nw8;
    j = k - seg * nw8;
    s = (seg == 0) ? w0 : (seg == 1) ? w1 : (seg == 2) ? w2 : w3;
    d = dw + (size_t)seg * DM * DM;
  }
  const float4* sp = reinterpret_cast<const float4*>(s);
  float4 a = sp[2 * j], b = sp[2 * j + 1];
  u16x8 o;
  o[0] = f2bf_bits(a.x); o[1] = f2bf_bits(a.y); o[2] = f2bf_bits(a.z); o[3] = f2bf_bits(a.w);
  o[4] = f2bf_bits(b.x); o[5] = f2bf_bits(b.y); o[6] = f2bf_bits(b.z); o[7] = f2bf_bits(b.w);
  reinterpret_cast<u16x8*>(d)[j] = o;
}

// ---------------- 3-buffer counted-vmcnt GEMM: C[M,N] = A[M,K] * B[N,K]^T ------
// BM=256, BN=128, BK=64, 512 thr = 8 waves (4M x 2N), per-wave 64x64.
// 3 LDS buffers; ONE barrier + ONE counted vmcnt(6) per K-tile (round-8 config:
// the measured best of this schedule family; BK=32, 4-wave 128x64, and
// stage-after-MFMA variants all regressed -14%/-67%/-4%).
template <int OUTM>
__global__ __launch_bounds__(512, 1) void gemm_3buf(
    const bf16_t* __restrict__ A, const bf16_t* __restrict__ B,
    void* __restrict__ Cq, void* __restrict__ Ck, void* __restrict__ Cv) {
  __shared__ bf16_t Asm[3][256 * 64];   // 96 KB
  __shared__ bf16_t Bsm[3][128 * 64];   // 48 KB
  const int tid = threadIdx.x;
  const int l = tid & 63, w = tid >> 6;
  const int wm = w >> 1, wn = w & 1;
  const int m0 = blockIdx.y * 256, n0 = blockIdx.x * 128;
  const int NT = DM / 64;   // 32

  auto SA = [&](int t, int buf, int s) {          // s = 0..3 (A: 256 rows)
    const int rowbase = s * 64 + w * 8;           // wave-uniform
    const int row = rowbase + (l >> 3);
    const int ug = (l & 7) ^ (row & 7);
    const int tc = (t < NT) ? t : 0;              // dummy clamp (keeps vmcnt uniform)
    gll16(A + (size_t)(m0 + row) * DM + tc * 64 + ug * 8,
          (char*)Asm[buf] + rowbase * 128);
  };
  auto SB = [&](int t, int buf, int s) {          // s = 0..1 (B: 128 rows)
    const int rowbase = s * 64 + w * 8;
    const int row = rowbase + (l >> 3);
    const int ug = (l & 7) ^ (row & 7);
    const int tc = (t < NT) ? t : 0;
    gll16(B + (size_t)(n0 + row) * DM + tc * 64 + ug * 8,
          (char*)Bsm[buf] + rowbase * 128);
  };

  f32x4 acc[4][4] = {};

  // Prologue: stage tiles 0 and 1 (6 loads each).
#pragma unroll
  for (int s = 0; s < 4; ++s) SA(0, 0, s);
  SB(0, 0, 0); SB(0, 0, 1);
#pragma unroll
  for (int s = 0; s < 4; ++s) SA(1, 1, s);
  SB(1, 1, 0); SB(1, 1, 1);
  asm volatile("s_waitcnt vmcnt(6)" ::: "memory");   // tile 0 complete
  __builtin_amdgcn_s_barrier();
  __builtin_amdgcn_sched_barrier(0);

  for (int j = 0; j < NT; ++j) {
    const int bj = j % 3, bs = (j + 2) % 3;
    const char* Ab_ = (const char*)Asm[bj];
    const char* Bb_ = (const char*)Bsm[bj];
    bf16x8 af[4][2], bfr[4][2];

    // ---- full-tile ds_read burst (16 x b128, swizzled) ----
#pragma unroll
    for (int mi = 0; mi < 4; ++mi)
#pragma unroll
      for (int kh = 0; kh < 2; ++kh) {
        const int row = wm * 64 + mi * 16 + (l & 15);
        const int u = (kh * 4 + (l >> 4)) ^ (row & 7);
        af[mi][kh] = *reinterpret_cast<const bf16x8*>(Ab_ + row * 128 + u * 16);
      }
#pragma unroll
    for (int ni = 0; ni < 4; ++ni)
#pragma unroll
      for (int kh = 0; kh < 2; ++kh) {
        const int row = wn * 64 + ni * 16 + (l & 15);
        const int u = (kh * 4 + (l >> 4)) ^ (row & 7);
        bfr[ni][kh] = *reinterpret_cast<const bf16x8*>(Bb_ + row * 128 + u * 16);
      }

    // ---- stage tile j+2 (6 x gll16) ----
    SA(j + 2, bs, 0); SA(j + 2, bs, 1); SA(j + 2, bs, 2); SA(j + 2, bs, 3);
    SB(j + 2, bs, 0); SB(j + 2, bs, 1);
    __builtin_amdgcn_sched_barrier(0);   // pin MFMAs below the stage-issues

    // ---- 32 MFMA; kh-outer => 16 independent chains per cluster ----
    __builtin_amdgcn_s_setprio(1);
#pragma unroll
    for (int kh = 0; kh < 2; ++kh)
#pragma unroll
      for (int mi = 0; mi < 4; ++mi)
#pragma unroll
        for (int ni = 0; ni < 4; ++ni)
          acc[mi][ni] = __builtin_amdgcn_mfma_f32_16x16x32_bf16(
              af[mi][kh], bfr[ni][kh], acc[mi][ni], 0, 0, 0);
    __builtin_amdgcn_s_setprio(0);

    // counted: only tile j+2's 6 loads may remain in flight -> tile j+1 ready
    asm volatile("s_waitcnt vmcnt(6)" ::: "memory");
    __builtin_amdgcn_s_barrier();
    __builtin_amdgcn_sched_barrier(0);
  }

  // ---- epilogue ----
  if constexpr (OUTM == 0) {
    const int proj = n0 >> 11;          // 0=Q, 1=K, 2=V (uniform per WG)
    const int nc0 = n0 & (DM - 1);
    if (proj < 2) {
      bf16_t* C = (bf16_t*)(proj == 0 ? Cq : Ck);
#pragma unroll
      for (int mi = 0; mi < 4; ++mi) {
        const int row = m0 + wm * 64 + mi * 16 + ((l >> 4) << 2);
#pragma unroll
        for (int ni = 0; ni < 4; ++ni) {
          const int col = nc0 + wn * 64 + ni * 16 + (l & 15);
#pragma unroll
          for (int r = 0; r < 4; ++r)
            C[(size_t)(row + r) * DM + col] = f2bf(acc[mi][ni][r]);
        }
      }
    } else {
      bf16_t* VT = (bf16_t*)Cv;
#pragma unroll
      for (int mi = 0; mi < 4; ++mi) {
        const int row = m0 + wm * 64 + mi * 16 + ((l >> 4) << 2);
        const int bb = row >> 11, tt = row & (TSEQ - 1);
#pragma unroll
        for (int ni = 0; ni < 4; ++ni) {
          const int col = nc0 + wn * 64 + ni * 16 + (l & 15);
          const int hh = col >> 7, dd = col & (HD - 1);
          bf16x4 pk;
#pragma unroll
          for (int r = 0; r < 4; ++r) pk[r] = f2bf(acc[mi][ni][r]);
          *reinterpret_cast<bf16x4*>(VT + (((size_t)bb * NH + hh) * HD + dd) * TSEQ + tt) = pk;
        }
      }
    }
  } else {
    float* C = (float*)Cq;
#pragma unroll
    for (int mi = 0; mi < 4; ++mi) {
      const int row = m0 + wm * 64 + mi * 16 + ((l >> 4) << 2);
#pragma unroll
      for (int ni = 0; ni < 4; ++ni) {
        const int col = n0 + wn * 64 + ni * 16 + (l & 15);
#pragma unroll
        for (int r = 0; r < 4; ++r)
          C[(size_t)(row + r) * DM + col] = acc[mi][ni][r];
      }
    }
  }
}

// ---------------- causal flash attention v6: kv-split wave pairs -----------------
// grid: (8, B*H) = 256 blocks. Block: 512 thr = 8 waves = 4 q-subblocks x 2 kv-halves.
// Block i runs q-tile i then q-tile 15-i (paired: 34 k-tiles each).
#define LDS_TOT 75776
__global__ __launch_bounds__(512, 2) void flash_attn(
    const bf16_t* __restrict__ Q, const bf16_t* __restrict__ Kx,
    const bf16_t* __restrict__ VT, bf16_t* __restrict__ O) {
  __shared__ __align__(16) char Lds[LDS_TOT];
  // staging (during loop): Ks[2] @0 (2x16 KB), Vs[2] @32768 (2x16 KB)
  // merge (after loop):   accbuf @0 (64 KB), ml @65536 (4 KB), ml2 @69632 (6 KB)

  const int tid = threadIdx.x;
  const int l = tid & 63, w = tid >> 6;
  const int hi = l >> 5, ln31 = l & 31;
  const int qw = w >> 1, kw = w & 1;
  const int bh = blockIdx.y;
  const int b = bh >> 4, h = bh & 15;
  const size_t base   = ((size_t)b * TSEQ) * DM + (size_t)h * HD;   // Q/K/O
  const size_t vtbase = ((size_t)b * NH + h) * HD * (size_t)TSEQ;   // V^T
  const float cc = 0.12752775f;  // (1/sqrt(128)) * log2(e)

  auto run_qtile = [&](int qb) {
    const int wq0 = qb * 128 + qw * 32;
    const int nt = 2 * qb + 2;

    // Q as B-operand: lane holds col q = ln31, k(d) = m*16 + hi*8 + j
    bf16x8 qf[8];
    {
      const bf16_t* qp = Q + base + (size_t)(wq0 + ln31) * DM + hi * 8;
#pragma unroll
      for (int m = 0; m < 8; ++m)
        qf[m] = *reinterpret_cast<const bf16x8*>(qp + m * 16);
    }

    f32x16 acc[4] = {};   // O_half: row q=crow(r,hi), col d = n*32 + ln31
    float mrow = -1e30f, lrow = 0.f;

    auto STAGE = [&](int t, int buf) {
#pragma unroll
      for (int c = 0; c < 2; ++c) {
        const int chunk = w * 2 + c;                   // 0..15
        const int krow = chunk * 4 + (l >> 4);
        const int u = l & 15;
        const int ug = (u & 8) | ((u ^ krow) & 7);
        gll16(Kx + base + (size_t)(t * 64 + krow) * DM + ug * 8,
              Lds + buf * 16384 + chunk * 1024);
      }
#pragma unroll
      for (int c = 0; c < 2; ++c) {
        const int ci = w * 2 + c;                      // 0..15
        const int d = ci * 8 + (l >> 3);
        const int ug = (l & 7) ^ (l >> 3);
        gll16(VT + vtbase + (size_t)d * TSEQ + t * 64 + ug * 8,
              Lds + 32768 + buf * 16384 + ci * 1024);
      }
    };

    STAGE(0, 0);
    __syncthreads();
    int cur = 0;

    for (int t = 0; t < nt; ++t) {
      if (t + 1 < nt) STAGE(t + 1, cur ^ 1);

      const bool active = (t * 64 + kw * 32 <= wq0 + 31);
      if (active) {
        // ---- S^T_half = K_half Q^T : 8 MFMA ----
        f32x16 s = {};
        const char* Kb_ = Lds + cur * 16384;
        const int kvr = kw * 32 + ln31;
#pragma unroll
        for (int m = 0; m < 8; ++m) {
          const int u = 2 * m + hi;
          const int uswz = (u & 8) | ((u ^ kvr) & 7);
          const bf16x8 kf = *reinterpret_cast<const bf16x8*>(Kb_ + kvr * 256 + uswz * 16);
          s = __builtin_amdgcn_mfma_f32_32x32x16_bf16(kf, qf[m], s, 0, 0, 0);
        }

        // ---- scale + causal mask (q = ln31, kv = t*64 + kw*32 + crow(r,hi)) ----
        float sv[16];
        const int qg = wq0 + ln31;
#pragma unroll
        for (int r = 0; r < 16; ++r) sv[r] = s[r] * cc;
        if (t * 64 + kw * 32 + 31 > wq0) {
#pragma unroll
          for (int r = 0; r < 16; ++r) {
            const int kvg = t * 64 + kw * 32 + (r & 3) + 8 * (r >> 2) + 4 * hi;
            if (kvg > qg) sv[r] = -3.0e38f;
          }
        }

        // ---- row max over this half (16 regs + cross-hi) ----
        float mt = sv[0];
#pragma unroll
        for (int r = 1; r < 16; ++r) mt = fmaxf(mt, sv[r]);
        mt = fmaxf(mt, __shfl_xor(mt, 32, 64));

        // T13 defer-max; redistribute scl q->crow via shfl
        if (__any(mt > mrow + 8.0f)) {
          const float mn = fmaxf(mrow, mt);
          const float scl = fast_exp2(mrow - mn);
          mrow = mn;
          lrow *= scl;
#pragma unroll
          for (int r = 0; r < 16; ++r) {
            const float sr = __shfl(scl, (r & 3) + 8 * (r >> 2) + 4 * hi, 64);
            acc[0][r] *= sr; acc[1][r] *= sr; acc[2][r] *= sr; acc[3][r] *= sr;
          }
        }

        // ---- P = exp2(S - m), row sum ----
        float rs = 0.f;
#pragma unroll
        for (int r = 0; r < 16; ++r) {
          const float p = fast_exp2(sv[r] - mrow);
          sv[r] = p;
          rs += p;
        }
        rs += __shfl_xor(rs, 32, 64);
        lrow += rs;

        // ---- cvt_pk + permlane32_swap: 2 PV A-frags (kv-slots kw*2, kw*2+1) ----
        u32 frag[2][4];
#pragma unroll
        for (int f = 0; f < 2; ++f) {
          const float* p = &sv[f * 8];
          u32 a1 = cvtpk(p[0], p[1]);
          u32 b1 = cvtpk(p[4], p[5]);
          pl32swap(a1, b1);
          u32 a2 = cvtpk(p[2], p[3]);
          u32 b2 = cvtpk(p[6], p[7]);
          pl32swap(a2, b2);
          frag[f][0] = a1; frag[f][1] = a2; frag[f][2] = b1; frag[f][3] = b2;
        }

        // ---- O_half += P_half V_half : 2 kv-slots x 4 d-tiles ----
        const char* Vb_ = Lds + 32768 + cur * 16384;
#pragma unroll
        for (int f = 0; f < 2; ++f) {
          const bf16x8 pf = __builtin_bit_cast(bf16x8, *reinterpret_cast<u32(*)[4]>(frag[f]));
#pragma unroll
          for (int n = 0; n < 4; ++n) {
            const int d = n * 32 + ln31;
            const int u = (kw * 2 + f) * 2 + hi;
            const int uswz = u ^ (d & 7);
            const bf16x8 vf = *reinterpret_cast<const bf16x8*>(Vb_ + d * 128 + uswz * 16);
            acc[n] = __builtin_amdgcn_mfma_f32_32x32x16_bf16(pf, vf, acc[n], 0, 0, 0);
          }
        }
      }
      __syncthreads();
      cur ^= 1;
    }

    // ---- kv-pair merge + store (split by d-halves) ----
    {
      // 1) write my NON-finalized accs: kw=0 writes acc[2],acc[3]; kw=1 acc[0],acc[1]
      float* accb = (float*)(Lds + qw * 16384 + kw * 8192);
      const int nb = (kw == 0) ? 2 : 0;
#pragma unroll
      for (int np = 0; np < 2; ++np) {
        float* dst = accb + np * 1024;
#pragma unroll
        for (int r = 0; r < 16; ++r) {
          const int row = (r & 3) + 8 * (r >> 2) + 4 * hi;
          dst[row * 32 + ln31] = acc[nb + np][r];
        }
      }
      float* mlp = (float*)(Lds + 65536 + qw * 1024 + kw * 512);
      if (hi == 0) { mlp[ln31] = mrow; mlp[32 + ln31] = lrow; }
      __syncthreads();

      // 2) merge scalars at lane = q
      const float* mlo = (float*)(Lds + 65536 + qw * 1024 + (kw ^ 1) * 512);
      const float mo = mlo[ln31], lo = mlo[32 + ln31];
      const float mm = fmaxf(mrow, mo);
      const float as = fast_exp2(mrow - mm);
      const float ao = fast_exp2(mo - mm);
      const float rln = fast_rcp(lrow * as + lo * ao);
      float* ml2p = (float*)(Lds + 69632 + qw * 1536 + kw * 768);
      if (hi == 0) { ml2p[ln31] = as; ml2p[32 + ln31] = ao; ml2p[64 + ln31] = rln; }
      __syncthreads();

      // 3) finalize my d-half: kw=0 -> d 0..63 (acc[0],acc[1]), kw=1 -> d 64..127
      const float* accoth = (float*)(Lds + qw * 16384 + (kw ^ 1) * 8192);
      const int nf = (kw == 0) ? 0 : 2;
#pragma unroll
      for (int r = 0; r < 16; ++r) {
        const int row = (r & 3) + 8 * (r >> 2) + 4 * hi;
        const float asr = ml2p[row];
        const float aor = ml2p[32 + row];
        const float rlr = ml2p[64 + row];
        const int q = wq0 + row;
        bf16_t* op = O + base + (size_t)q * DM + ln31;
#pragma unroll
        for (int np = 0; np < 2; ++np) {
          const float vo = (acc[nf + np][r] * asr + accoth[np * 1024 + row * 32 + ln31] * aor) * rlr;
          op[(kw * 2 + np) * 32] = f2bf(vo);
        }
      }
      __syncthreads();   // LDS safe for next leg's staging
    }
  };

  const int i = blockIdx.x;               // 0..7
  run_qtile(i);                           // short leg: 2i+2 k-tiles
  run_qtile((int)(TSEQ / 128) - 1 - i);   // long leg: 32-2i k-tiles (total 34)
}

// ---------------- launch ----------------
extern "C" void kernel_launch(void* const* d_in, const int* in_sizes, int n_in,
                              void* d_out, int out_size, void* d_ws, size_t ws_size,
                              hipStream_t stream) {
  (void)in_sizes; (void)n_in; (void)out_size; (void)ws_size;
  const float* x  = (const float*)d_in[0];
  const float* wq = (const float*)d_in[1];
  const float* wk = (const float*)d_in[2];
  const float* wv = (const float*)d_in[3];
  const float* wo = (const float*)d_in[4];
  float* out = (float*)d_out;

  const size_t nx = (size_t)MROWS * DM;  // 8388608
  const size_t nw = (size_t)DM * DM;     // 4194304
  bf16_t* xb  = (bf16_t*)d_ws;
  bf16_t* wqb = xb + nx;                 // wq/wk/wv/wo contiguous bf16
  bf16_t* Qb  = wqb + 4 * nw;
  bf16_t* Kb  = Qb + nx;
  bf16_t* Vtb = Kb + nx;   // V^T [B][H][d][t]
  bf16_t* Ab  = Vtb + nx;
  bf16_t* wob = wqb + 3 * nw;

  const int nx8 = (int)(nx / 8);         // 1048576
  const int nw8 = (int)(nw / 8);         // 524288
  const int ntot = nx8 + 4 * nw8;        // 3145728
  cvt_all<<<ntot / 256, 256, 0, stream>>>(x, wq, wk, wv, wo, xb, wqb, nx8, nw8);

  // fused QKV: B rows 0..2047 -> Q, 2048..4095 -> K, 4096..6143 -> V(T)
  gemm_3buf<0><<<dim3(3 * DM / 128, MROWS / 256), 512, 0, stream>>>(
      xb, wqb, Qb, Kb, Vtb);

  flash_attn<<<dim3(TSEQ / 128 / 2, BATCH * NH), 512, 0, stream>>>(Qb, Kb, Vtb, Ab);

  gemm_3buf<1><<<dim3(DM / 128, MROWS / 256), 512, 0, stream>>>(
      Ab, wob, out, nullptr, nullptr);
}

// Round 16
// 212.193 us; speedup vs baseline: 1.1524x; 1.0440x over previous
//
#include <hip/hip_runtime.h>

#define DM    2048
#define NH    16
#define HD    128
#define TSEQ  2048
#define BATCH 2
#define MROWS (BATCH * TSEQ)   // 4096

typedef __bf16 bf16_t;
typedef __bf16 bf16x8 __attribute__((ext_vector_type(8)));
typedef __bf16 bf16x4 __attribute__((ext_vector_type(4)));
typedef float  f32x4  __attribute__((ext_vector_type(4)));
typedef float  f32x16 __attribute__((ext_vector_type(16)));
typedef unsigned short u16x8 __attribute__((ext_vector_type(8)));
typedef unsigned int   u32;

static __device__ __forceinline__ unsigned short f2bf_bits(float f) {
  unsigned u = __builtin_bit_cast(unsigned, f);
  u += 0x7fffu + ((u >> 16) & 1u);            // round-to-nearest-even
  return (unsigned short)(u >> 16);
}
static __device__ __forceinline__ bf16_t f2bf(float f) {
  unsigned short h = f2bf_bits(f);
  return __builtin_bit_cast(bf16_t, h);
}

static __device__ __forceinline__ void gll16(const void* g, void* lds) {
  __builtin_amdgcn_global_load_lds(
      (const __attribute__((address_space(1))) unsigned int*)g,
      (__attribute__((address_space(3))) unsigned int*)lds, 16, 0, 0);
}

static __device__ __forceinline__ float fast_exp2(float x) {
#if __has_builtin(__builtin_amdgcn_exp2f)
  return __builtin_amdgcn_exp2f(x);
#else
  return exp2f(x);
#endif
}
static __device__ __forceinline__ float fast_rcp(float x) {
#if __has_builtin(__builtin_amdgcn_rcpf)
  return __builtin_amdgcn_rcpf(x);
#else
  return 1.0f / x;
#endif
}

// v_cvt_pk_bf16_f32: dst.lo16 = bf16(a), dst.hi16 = bf16(b)
static __device__ __forceinline__ u32 cvtpk(float a, float b) {
  u32 d;
  asm("v_cvt_pk_bf16_f32 %0, %1, %2" : "=v"(d) : "v"(a), "v"(b));
  return d;
}
// v_permlane32_swap_b32 a, b: a.hi32lanes <-> b.lo32lanes
static __device__ __forceinline__ void pl32swap(u32& a, u32& b) {
  asm volatile("v_permlane32_swap_b32 %0, %1" : "+v"(a), "+v"(b));
}

// ---------------- fused fp32 -> bf16 convert: x + 4 weights, ONE dispatch ------
__global__ void cvt_all(const float* __restrict__ x,
                        const float* __restrict__ w0, const float* __restrict__ w1,
                        const float* __restrict__ w2, const float* __restrict__ w3,
                        bf16_t* __restrict__ dx, bf16_t* __restrict__ dw,
                        int nx8, int nw8) {
  const int i = blockIdx.x * blockDim.x + threadIdx.x;
  const float* s;
  bf16_t* d;
  int j;
  if (i < nx8) {
    s = x; d = dx; j = i;
  } else {
    const int k = i - nx8;
    const int seg = k / nw8;
    j = k - seg * nw8;
    s = (seg == 0) ? w0 : (seg == 1) ? w1 : (seg == 2) ? w2 : w3;
    d = dw + (size_t)seg * DM * DM;
  }
  const float4* sp = reinterpret_cast<const float4*>(s);
  float4 a = sp[2 * j], b = sp[2 * j + 1];
  u16x8 o;
  o[0] = f2bf_bits(a.x); o[1] = f2bf_bits(a.y); o[2] = f2bf_bits(a.z); o[3] = f2bf_bits(a.w);
  o[4] = f2bf_bits(b.x); o[5] = f2bf_bits(b.y); o[6] = f2bf_bits(b.z); o[7] = f2bf_bits(b.w);
  reinterpret_cast<u16x8*>(d)[j] = o;
}

// ---------------- gemm256: 256x256 tile, per-wave 128x64 (Q/K projections) ----
// BM=BN=256, BK=64, 512 thr = 8 waves (2M x 4N). reads/MFMA = 24/64 = 0.375
// (vs 0.5 of the 256x128 kernel) at 2 waves/SIMD. LDS 160 KB: A 3-buf (96 KB,
// stage distance 2) + B 2-buf (64 KB, distance 1). Race-free: A slot (j+2)%3
// untouched by tiles j/j+1; B slot (j+1)%2 != j%2, and all tile-j reads are
// register-consumed (lgkmcnt before MFMA) before the tile-end barrier.
// End-of-tile vmcnt(4): drains A(j+1)+B(j+1), floats A(j+2)'s 4 loads.
__global__ __launch_bounds__(512, 1) void gemm256(
    const bf16_t* __restrict__ A, const bf16_t* __restrict__ B,
    bf16_t* __restrict__ Cq, bf16_t* __restrict__ Ck) {
  __shared__ bf16_t Asm[3][256 * 64];   // 96 KB
  __shared__ bf16_t Bsm[2][256 * 64];   // 64 KB
  const int tid = threadIdx.x;
  const int l = tid & 63, w = tid >> 6;
  const int wm = w >> 2, wn = w & 3;        // 2M x 4N
  const int m0 = blockIdx.y * 256, n0 = blockIdx.x * 256;
  const int NT = DM / 64;   // 32

  auto SA = [&](int t, int buf, int s) {          // s = 0..3 (A: 256 rows)
    const int rowbase = s * 64 + w * 8;           // wave-uniform
    const int row = rowbase + (l >> 3);
    const int ug = (l & 7) ^ (row & 7);
    const int tc = (t < NT) ? t : 0;              // dummy clamp (keeps vmcnt uniform)
    gll16(A + (size_t)(m0 + row) * DM + tc * 64 + ug * 8,
          (char*)Asm[buf] + rowbase * 128);
  };
  auto SB = [&](int t, int buf, int s) {          // s = 0..3 (B: 256 rows)
    const int rowbase = s * 64 + w * 8;
    const int row = rowbase + (l >> 3);
    const int ug = (l & 7) ^ (row & 7);
    const int tc = (t < NT) ? t : 0;
    gll16(B + (size_t)(n0 + row) * DM + tc * 64 + ug * 8,
          (char*)Bsm[buf] + rowbase * 128);
  };

  f32x4 acc[8][4] = {};

  // Prologue: A(0), B(0), A(1)  (queue: A0[4], B0[4], A1[4])
#pragma unroll
  for (int s = 0; s < 4; ++s) SA(0, 0, s);
#pragma unroll
  for (int s = 0; s < 4; ++s) SB(0, 0, s);
#pragma unroll
  for (int s = 0; s < 4; ++s) SA(1, 1, s);
  asm volatile("s_waitcnt vmcnt(4)" ::: "memory");   // A0,B0 complete; A1 floats
  __builtin_amdgcn_s_barrier();
  __builtin_amdgcn_sched_barrier(0);

  for (int j = 0; j < NT; ++j) {
    const int bjA = j % 3, bjB = j & 1;
    const int bsA = (j + 2) % 3, bsB = (j + 1) & 1;
    const char* Ab_ = (const char*)Asm[bjA];
    const char* Bb_ = (const char*)Bsm[bjB];

    // ---- sub-phase kh=0: 12 ds_read | stage B(j+1) | 32 MFMA ----
    {
      bf16x8 af[8], bfr[4];
#pragma unroll
      for (int mi = 0; mi < 8; ++mi) {
        const int row = wm * 128 + mi * 16 + (l & 15);
        const int u = (l >> 4) ^ (row & 7);
        af[mi] = *reinterpret_cast<const bf16x8*>(Ab_ + row * 128 + u * 16);
      }
#pragma unroll
      for (int ni = 0; ni < 4; ++ni) {
        const int row = wn * 64 + ni * 16 + (l & 15);
        const int u = (l >> 4) ^ (row & 7);
        bfr[ni] = *reinterpret_cast<const bf16x8*>(Bb_ + row * 128 + u * 16);
      }
      SB(j + 1, bsB, 0); SB(j + 1, bsB, 1); SB(j + 1, bsB, 2); SB(j + 1, bsB, 3);
      __builtin_amdgcn_sched_barrier(0);
      __builtin_amdgcn_s_setprio(1);
#pragma unroll
      for (int mi = 0; mi < 8; ++mi)
#pragma unroll
        for (int ni = 0; ni < 4; ++ni)
          acc[mi][ni] = __builtin_amdgcn_mfma_f32_16x16x32_bf16(
              af[mi], bfr[ni], acc[mi][ni], 0, 0, 0);
      __builtin_amdgcn_s_setprio(0);
    }

    // ---- sub-phase kh=1: 12 ds_read | stage A(j+2) | 32 MFMA ----
    {
      bf16x8 af[8], bfr[4];
#pragma unroll
      for (int mi = 0; mi < 8; ++mi) {
        const int row = wm * 128 + mi * 16 + (l & 15);
        const int u = (4 + (l >> 4)) ^ (row & 7);
        af[mi] = *reinterpret_cast<const bf16x8*>(Ab_ + row * 128 + u * 16);
      }
#pragma unroll
      for (int ni = 0; ni < 4; ++ni) {
        const int row = wn * 64 + ni * 16 + (l & 15);
        const int u = (4 + (l >> 4)) ^ (row & 7);
        bfr[ni] = *reinterpret_cast<const bf16x8*>(Bb_ + row * 128 + u * 16);
      }
      SA(j + 2, bsA, 0); SA(j + 2, bsA, 1); SA(j + 2, bsA, 2); SA(j + 2, bsA, 3);
      __builtin_amdgcn_sched_barrier(0);
      __builtin_amdgcn_s_setprio(1);
#pragma unroll
      for (int mi = 0; mi < 8; ++mi)
#pragma unroll
        for (int ni = 0; ni < 4; ++ni)
          acc[mi][ni] = __builtin_amdgcn_mfma_f32_16x16x32_bf16(
              af[mi], bfr[ni], acc[mi][ni], 0, 0, 0);
      __builtin_amdgcn_s_setprio(0);
    }

    // counted: A(j+1)+B(j+1) drained; only A(j+2)'s 4 loads remain
    asm volatile("s_waitcnt vmcnt(4)" ::: "memory");
    __builtin_amdgcn_s_barrier();
    __builtin_amdgcn_sched_barrier(0);
  }

  // ---- epilogue: n0 in [0,4096) -> proj 0 = Q, 1 = K ----
  bf16_t* C = (n0 >> 11) ? Ck : Cq;
  const int nc0 = n0 & (DM - 1);
#pragma unroll
  for (int mi = 0; mi < 8; ++mi) {
    const int row = m0 + wm * 128 + mi * 16 + ((l >> 4) << 2);
#pragma unroll
    for (int ni = 0; ni < 4; ++ni) {
      const int col = nc0 + wn * 64 + ni * 16 + (l & 15);
#pragma unroll
      for (int r = 0; r < 4; ++r)
        C[(size_t)(row + r) * DM + col] = f2bf(acc[mi][ni][r]);
    }
  }
}

// ---------------- 3-buffer counted-vmcnt GEMM (round-8 config, proven) --------
// OUTM: 1 = fp32 row-major to Cq (AO).  2 = V-only: B spans 2048 cols, output
// written as per-head V^T [B][H][d][t] to Cv.
template <int OUTM>
__global__ __launch_bounds__(512, 1) void gemm_3buf(
    const bf16_t* __restrict__ A, const bf16_t* __restrict__ B,
    void* __restrict__ Cq, void* __restrict__ Cv) {
  __shared__ bf16_t Asm[3][256 * 64];   // 96 KB
  __shared__ bf16_t Bsm[3][128 * 64];   // 48 KB
  const int tid = threadIdx.x;
  const int l = tid & 63, w = tid >> 6;
  const int wm = w >> 1, wn = w & 1;
  const int m0 = blockIdx.y * 256, n0 = blockIdx.x * 128;
  const int NT = DM / 64;   // 32

  auto SA = [&](int t, int buf, int s) {          // s = 0..3 (A: 256 rows)
    const int rowbase = s * 64 + w * 8;           // wave-uniform
    const int row = rowbase + (l >> 3);
    const int ug = (l & 7) ^ (row & 7);
    const int tc = (t < NT) ? t : 0;              // dummy clamp (keeps vmcnt uniform)
    gll16(A + (size_t)(m0 + row) * DM + tc * 64 + ug * 8,
          (char*)Asm[buf] + rowbase * 128);
  };
  auto SB = [&](int t, int buf, int s) {          // s = 0..1 (B: 128 rows)
    const int rowbase = s * 64 + w * 8;
    const int row = rowbase + (l >> 3);
    const int ug = (l & 7) ^ (row & 7);
    const int tc = (t < NT) ? t : 0;
    gll16(B + (size_t)(n0 + row) * DM + tc * 64 + ug * 8,
          (char*)Bsm[buf] + rowbase * 128);
  };

  f32x4 acc[4][4] = {};

  // Prologue: stage tiles 0 and 1 (6 loads each).
#pragma unroll
  for (int s = 0; s < 4; ++s) SA(0, 0, s);
  SB(0, 0, 0); SB(0, 0, 1);
#pragma unroll
  for (int s = 0; s < 4; ++s) SA(1, 1, s);
  SB(1, 1, 0); SB(1, 1, 1);
  asm volatile("s_waitcnt vmcnt(6)" ::: "memory");   // tile 0 complete
  __builtin_amdgcn_s_barrier();
  __builtin_amdgcn_sched_barrier(0);

  for (int j = 0; j < NT; ++j) {
    const int bj = j % 3, bs = (j + 2) % 3;
    const char* Ab_ = (const char*)Asm[bj];
    const char* Bb_ = (const char*)Bsm[bj];
    bf16x8 af[4][2], bfr[4][2];

    // ---- full-tile ds_read burst (16 x b128, swizzled) ----
#pragma unroll
    for (int mi = 0; mi < 4; ++mi)
#pragma unroll
      for (int kh = 0; kh < 2; ++kh) {
        const int row = wm * 64 + mi * 16 + (l & 15);
        const int u = (kh * 4 + (l >> 4)) ^ (row & 7);
        af[mi][kh] = *reinterpret_cast<const bf16x8*>(Ab_ + row * 128 + u * 16);
      }
#pragma unroll
    for (int ni = 0; ni < 4; ++ni)
#pragma unroll
      for (int kh = 0; kh < 2; ++kh) {
        const int row = wn * 64 + ni * 16 + (l & 15);
        const int u = (kh * 4 + (l >> 4)) ^ (row & 7);
        bfr[ni][kh] = *reinterpret_cast<const bf16x8*>(Bb_ + row * 128 + u * 16);
      }

    // ---- stage tile j+2 (6 x gll16) ----
    SA(j + 2, bs, 0); SA(j + 2, bs, 1); SA(j + 2, bs, 2); SA(j + 2, bs, 3);
    SB(j + 2, bs, 0); SB(j + 2, bs, 1);
    __builtin_amdgcn_sched_barrier(0);   // pin MFMAs below the stage-issues

    // ---- 32 MFMA; kh-outer => 16 independent chains per cluster ----
    __builtin_amdgcn_s_setprio(1);
#pragma unroll
    for (int kh = 0; kh < 2; ++kh)
#pragma unroll
      for (int mi = 0; mi < 4; ++mi)
#pragma unroll
        for (int ni = 0; ni < 4; ++ni)
          acc[mi][ni] = __builtin_amdgcn_mfma_f32_16x16x32_bf16(
              af[mi][kh], bfr[ni][kh], acc[mi][ni], 0, 0, 0);
    __builtin_amdgcn_s_setprio(0);

    // counted: only tile j+2's 6 loads may remain in flight -> tile j+1 ready
    asm volatile("s_waitcnt vmcnt(6)" ::: "memory");
    __builtin_amdgcn_s_barrier();
    __builtin_amdgcn_sched_barrier(0);
  }

  // ---- epilogue ----
  if constexpr (OUTM == 2) {
    // V-only: col = n0 + ... in [0,2048); write per-head V^T
    bf16_t* VT = (bf16_t*)Cv;
#pragma unroll
    for (int mi = 0; mi < 4; ++mi) {
      const int row = m0 + wm * 64 + mi * 16 + ((l >> 4) << 2);
      const int bb = row >> 11, tt = row & (TSEQ - 1);
#pragma unroll
      for (int ni = 0; ni < 4; ++ni) {
        const int col = n0 + wn * 64 + ni * 16 + (l & 15);
        const int hh = col >> 7, dd = col & (HD - 1);
        bf16x4 pk;
#pragma unroll
        for (int r = 0; r < 4; ++r) pk[r] = f2bf(acc[mi][ni][r]);
        *reinterpret_cast<bf16x4*>(VT + (((size_t)bb * NH + hh) * HD + dd) * TSEQ + tt) = pk;
      }
    }
  } else {
    float* C = (float*)Cq;
#pragma unroll
    for (int mi = 0; mi < 4; ++mi) {
      const int row = m0 + wm * 64 + mi * 16 + ((l >> 4) << 2);
#pragma unroll
      for (int ni = 0; ni < 4; ++ni) {
        const int col = n0 + wn * 64 + ni * 16 + (l & 15);
#pragma unroll
        for (int r = 0; r < 4; ++r)
          C[(size_t)(row + r) * DM + col] = acc[mi][ni][r];
      }
    }
  }
}

// ---------------- causal flash attention v6: kv-split wave pairs -----------------
// grid: (8, B*H) = 256 blocks. Block: 512 thr = 8 waves = 4 q-subblocks x 2 kv-halves.
// Block i runs q-tile i then q-tile 15-i (paired: 34 k-tiles each).
#define LDS_TOT 75776
__global__ __launch_bounds__(512, 2) void flash_attn(
    const bf16_t* __restrict__ Q, const bf16_t* __restrict__ Kx,
    const bf16_t* __restrict__ VT, bf16_t* __restrict__ O) {
  __shared__ __align__(16) char Lds[LDS_TOT];
  // staging (during loop): Ks[2] @0 (2x16 KB), Vs[2] @32768 (2x16 KB)
  // merge (after loop):   accbuf @0 (64 KB), ml @65536 (4 KB), ml2 @69632 (6 KB)

  const int tid = threadIdx.x;
  const int l = tid & 63, w = tid >> 6;
  const int hi = l >> 5, ln31 = l & 31;
  const int qw = w >> 1, kw = w & 1;
  const int bh = blockIdx.y;
  const int b = bh >> 4, h = bh & 15;
  const size_t base   = ((size_t)b * TSEQ) * DM + (size_t)h * HD;   // Q/K/O
  const size_t vtbase = ((size_t)b * NH + h) * HD * (size_t)TSEQ;   // V^T
  const float cc = 0.12752775f;  // (1/sqrt(128)) * log2(e)

  auto run_qtile = [&](int qb) {
    const int wq0 = qb * 128 + qw * 32;
    const int nt = 2 * qb + 2;

    // Q as B-operand: lane holds col q = ln31, k(d) = m*16 + hi*8 + j
    bf16x8 qf[8];
    {
      const bf16_t* qp = Q + base + (size_t)(wq0 + ln31) * DM + hi * 8;
#pragma unroll
      for (int m = 0; m < 8; ++m)
        qf[m] = *reinterpret_cast<const bf16x8*>(qp + m * 16);
    }

    f32x16 acc[4] = {};   // O_half: row q=crow(r,hi), col d = n*32 + ln31
    float mrow = -1e30f, lrow = 0.f;

    auto STAGE = [&](int t, int buf) {
#pragma unroll
      for (int c = 0; c < 2; ++c) {
        const int chunk = w * 2 + c;                   // 0..15
        const int krow = chunk * 4 + (l >> 4);
        const int u = l & 15;
        const int ug = (u & 8) | ((u ^ krow) & 7);
        gll16(Kx + base + (size_t)(t * 64 + krow) * DM + ug * 8,
              Lds + buf * 16384 + chunk * 1024);
      }
#pragma unroll
      for (int c = 0; c < 2; ++c) {
        const int ci = w * 2 + c;                      // 0..15
        const int d = ci * 8 + (l >> 3);
        const int ug = (l & 7) ^ (l >> 3);
        gll16(VT + vtbase + (size_t)d * TSEQ + t * 64 + ug * 8,
              Lds + 32768 + buf * 16384 + ci * 1024);
      }
    };

    STAGE(0, 0);
    __syncthreads();
    int cur = 0;

    for (int t = 0; t < nt; ++t) {
      if (t + 1 < nt) STAGE(t + 1, cur ^ 1);

      const bool active = (t * 64 + kw * 32 <= wq0 + 31);
      if (active) {
        // ---- S^T_half = K_half Q^T : 8 MFMA ----
        f32x16 s = {};
        const char* Kb_ = Lds + cur * 16384;
        const int kvr = kw * 32 + ln31;
#pragma unroll
        for (int m = 0; m < 8; ++m) {
          const int u = 2 * m + hi;
          const int uswz = (u & 8) | ((u ^ kvr) & 7);
          const bf16x8 kf = *reinterpret_cast<const bf16x8*>(Kb_ + kvr * 256 + uswz * 16);
          s = __builtin_amdgcn_mfma_f32_32x32x16_bf16(kf, qf[m], s, 0, 0, 0);
        }

        // ---- scale + causal mask (q = ln31, kv = t*64 + kw*32 + crow(r,hi)) ----
        float sv[16];
        const int qg = wq0 + ln31;
#pragma unroll
        for (int r = 0; r < 16; ++r) sv[r] = s[r] * cc;
        if (t * 64 + kw * 32 + 31 > wq0) {
#pragma unroll
          for (int r = 0; r < 16; ++r) {
            const int kvg = t * 64 + kw * 32 + (r & 3) + 8 * (r >> 2) + 4 * hi;
            if (kvg > qg) sv[r] = -3.0e38f;
          }
        }

        // ---- row max over this half (16 regs + cross-hi) ----
        float mt = sv[0];
#pragma unroll
        for (int r = 1; r < 16; ++r) mt = fmaxf(mt, sv[r]);
        mt = fmaxf(mt, __shfl_xor(mt, 32, 64));

        // T13 defer-max; redistribute scl q->crow via shfl
        if (__any(mt > mrow + 8.0f)) {
          const float mn = fmaxf(mrow, mt);
          const float scl = fast_exp2(mrow - mn);
          mrow = mn;
          lrow *= scl;
#pragma unroll
          for (int r = 0; r < 16; ++r) {
            const float sr = __shfl(scl, (r & 3) + 8 * (r >> 2) + 4 * hi, 64);
            acc[0][r] *= sr; acc[1][r] *= sr; acc[2][r] *= sr; acc[3][r] *= sr;
          }
        }

        // ---- P = exp2(S - m), row sum ----
        float rs = 0.f;
#pragma unroll
        for (int r = 0; r < 16; ++r) {
          const float p = fast_exp2(sv[r] - mrow);
          sv[r] = p;
          rs += p;
        }
        rs += __shfl_xor(rs, 32, 64);
        lrow += rs;

        // ---- cvt_pk + permlane32_swap: 2 PV A-frags (kv-slots kw*2, kw*2+1) ----
        u32 frag[2][4];
#pragma unroll
        for (int f = 0; f < 2; ++f) {
          const float* p = &sv[f * 8];
          u32 a1 = cvtpk(p[0], p[1]);
          u32 b1 = cvtpk(p[4], p[5]);
          pl32swap(a1, b1);
          u32 a2 = cvtpk(p[2], p[3]);
          u32 b2 = cvtpk(p[6], p[7]);
          pl32swap(a2, b2);
          frag[f][0] = a1; frag[f][1] = a2; frag[f][2] = b1; frag[f][3] = b2;
        }

        // ---- O_half += P_half V_half : 2 kv-slots x 4 d-tiles ----
        const char* Vb_ = Lds + 32768 + cur * 16384;
#pragma unroll
        for (int f = 0; f < 2; ++f) {
          const bf16x8 pf = __builtin_bit_cast(bf16x8, *reinterpret_cast<u32(*)[4]>(frag[f]));
#pragma unroll
          for (int n = 0; n < 4; ++n) {
            const int d = n * 32 + ln31;
            const int u = (kw * 2 + f) * 2 + hi;
            const int uswz = u ^ (d & 7);
            const bf16x8 vf = *reinterpret_cast<const bf16x8*>(Vb_ + d * 128 + uswz * 16);
            acc[n] = __builtin_amdgcn_mfma_f32_32x32x16_bf16(pf, vf, acc[n], 0, 0, 0);
          }
        }
      }
      __syncthreads();
      cur ^= 1;
    }

    // ---- kv-pair merge + store (split by d-halves) ----
    {
      // 1) write my NON-finalized accs: kw=0 writes acc[2],acc[3]; kw=1 acc[0],acc[1]
      float* accb = (float*)(Lds + qw * 16384 + kw * 8192);
      const int nb = (kw == 0) ? 2 : 0;
#pragma unroll
      for (int np = 0; np < 2; ++np) {
        float* dst = accb + np * 1024;
#pragma unroll
        for (int r = 0; r < 16; ++r) {
          const int row = (r & 3) + 8 * (r >> 2) + 4 * hi;
          dst[row * 32 + ln31] = acc[nb + np][r];
        }
      }
      float* mlp = (float*)(Lds + 65536 + qw * 1024 + kw * 512);
      if (hi == 0) { mlp[ln31] = mrow; mlp[32 + ln31] = lrow; }
      __syncthreads();

      // 2) merge scalars at lane = q
      const float* mlo = (float*)(Lds + 65536 + qw * 1024 + (kw ^ 1) * 512);
      const float mo = mlo[ln31], lo = mlo[32 + ln31];
      const float mm = fmaxf(mrow, mo);
      const float as = fast_exp2(mrow - mm);
      const float ao = fast_exp2(mo - mm);
      const float rln = fast_rcp(lrow * as + lo * ao);
      float* ml2p = (float*)(Lds + 69632 + qw * 1536 + kw * 768);
      if (hi == 0) { ml2p[ln31] = as; ml2p[32 + ln31] = ao; ml2p[64 + ln31] = rln; }
      __syncthreads();

      // 3) finalize my d-half: kw=0 -> d 0..63 (acc[0],acc[1]), kw=1 -> d 64..127
      const float* accoth = (float*)(Lds + qw * 16384 + (kw ^ 1) * 8192);
      const int nf = (kw == 0) ? 0 : 2;
#pragma unroll
      for (int r = 0; r < 16; ++r) {
        const int row = (r & 3) + 8 * (r >> 2) + 4 * hi;
        const float asr = ml2p[row];
        const float aor = ml2p[32 + row];
        const float rlr = ml2p[64 + row];
        const int q = wq0 + row;
        bf16_t* op = O + base + (size_t)q * DM + ln31;
#pragma unroll
        for (int np = 0; np < 2; ++np) {
          const float vo = (acc[nf + np][r] * asr + accoth[np * 1024 + row * 32 + ln31] * aor) * rlr;
          op[(kw * 2 + np) * 32] = f2bf(vo);
        }
      }
      __syncthreads();   // LDS safe for next leg's staging
    }
  };

  const int i = blockIdx.x;               // 0..7
  run_qtile(i);                           // short leg: 2i+2 k-tiles
  run_qtile((int)(TSEQ / 128) - 1 - i);   // long leg: 32-2i k-tiles (total 34)
}

// ---------------- launch ----------------
extern "C" void kernel_launch(void* const* d_in, const int* in_sizes, int n_in,
                              void* d_out, int out_size, void* d_ws, size_t ws_size,
                              hipStream_t stream) {
  (void)in_sizes; (void)n_in; (void)out_size; (void)ws_size;
  const float* x  = (const float*)d_in[0];
  const float* wq = (const float*)d_in[1];
  const float* wk = (const float*)d_in[2];
  const float* wv = (const float*)d_in[3];
  const float* wo = (const float*)d_in[4];
  float* out = (float*)d_out;

  const size_t nx = (size_t)MROWS * DM;  // 8388608
  const size_t nw = (size_t)DM * DM;     // 4194304
  bf16_t* xb  = (bf16_t*)d_ws;
  bf16_t* wqb = xb + nx;                 // wq/wk/wv/wo contiguous bf16
  bf16_t* wvb = wqb + 2 * nw;
  bf16_t* wob = wqb + 3 * nw;
  bf16_t* Qb  = wqb + 4 * nw;
  bf16_t* Kb  = Qb + nx;
  bf16_t* Vtb = Kb + nx;   // V^T [B][H][d][t]
  bf16_t* Ab  = Vtb + nx;

  const int nx8 = (int)(nx / 8);         // 1048576
  const int nw8 = (int)(nw / 8);         // 524288
  const int ntot = nx8 + 4 * nw8;        // 3145728
  cvt_all<<<ntot / 256, 256, 0, stream>>>(x, wq, wk, wv, wo, xb, wqb, nx8, nw8);

  // Q,K projections: 256x256 tiles, cols 0..4095 of fused [wq;wk]
  gemm256<<<dim3(2 * DM / 256, MROWS / 256), 512, 0, stream>>>(xb, wqb, Qb, Kb);
  // V projection: proven 256x128 kernel, V^T epilogue
  gemm_3buf<2><<<dim3(DM / 128, MROWS / 256), 512, 0, stream>>>(
      xb, wvb, nullptr, Vtb);

  flash_attn<<<dim3(TSEQ / 128 / 2, BATCH * NH), 512, 0, stream>>>(Qb, Kb, Vtb, Ab);

  gemm_3buf<1><<<dim3(DM / 128, MROWS / 256), 512, 0, stream>>>(
      Ab, wob, out, nullptr);
}

// Round 17
// 208.105 us; speedup vs baseline: 1.1750x; 1.0196x over previous
//
#include <hip/hip_runtime.h>

#define DM    2048
#define NH    16
#define HD    128
#define TSEQ  2048
#define BATCH 2
#define MROWS (BATCH * TSEQ)   // 4096

typedef __bf16 bf16_t;
typedef __bf16 bf16x8 __attribute__((ext_vector_type(8)));
typedef __bf16 bf16x4 __attribute__((ext_vector_type(4)));
typedef float  f32x4  __attribute__((ext_vector_type(4)));
typedef float  f32x16 __attribute__((ext_vector_type(16)));
typedef unsigned short u16x8 __attribute__((ext_vector_type(8)));
typedef unsigned int   u32;

static __device__ __forceinline__ unsigned short f2bf_bits(float f) {
  unsigned u = __builtin_bit_cast(unsigned, f);
  u += 0x7fffu + ((u >> 16) & 1u);            // round-to-nearest-even
  return (unsigned short)(u >> 16);
}
static __device__ __forceinline__ bf16_t f2bf(float f) {
  unsigned short h = f2bf_bits(f);
  return __builtin_bit_cast(bf16_t, h);
}

static __device__ __forceinline__ void gll16(const void* g, void* lds) {
  __builtin_amdgcn_global_load_lds(
      (const __attribute__((address_space(1))) unsigned int*)g,
      (__attribute__((address_space(3))) unsigned int*)lds, 16, 0, 0);
}

static __device__ __forceinline__ float fast_exp2(float x) {
#if __has_builtin(__builtin_amdgcn_exp2f)
  return __builtin_amdgcn_exp2f(x);
#else
  return exp2f(x);
#endif
}
static __device__ __forceinline__ float fast_rcp(float x) {
#if __has_builtin(__builtin_amdgcn_rcpf)
  return __builtin_amdgcn_rcpf(x);
#else
  return 1.0f / x;
#endif
}

// v_cvt_pk_bf16_f32: dst.lo16 = bf16(a), dst.hi16 = bf16(b)
static __device__ __forceinline__ u32 cvtpk(float a, float b) {
  u32 d;
  asm("v_cvt_pk_bf16_f32 %0, %1, %2" : "=v"(d) : "v"(a), "v"(b));
  return d;
}
// v_permlane32_swap_b32 a, b: a.hi32lanes <-> b.lo32lanes
static __device__ __forceinline__ void pl32swap(u32& a, u32& b) {
  asm volatile("v_permlane32_swap_b32 %0, %1" : "+v"(a), "+v"(b));
}

// T1 XCD swizzle: grids here are exactly 256 WGs (divisible by 8 XCDs), so the
// simple bijection f' = (f%8)*(nwg/8) + f/8 gives each XCD a CONTIGUOUS chunk
// of flat ids -> neighboring tiles (shared A-panels / shared KV-heads) hit the
// same per-XCD L2 instead of being re-fetched 8x from HBM.
static __device__ __forceinline__ void xcd_swz(int& bx, int& by) {
  const int gx = (int)gridDim.x;
  const int nwg = gx * (int)gridDim.y;
  const int f = (int)blockIdx.y * gx + (int)blockIdx.x;
  const int nf = (f & 7) * (nwg >> 3) + (f >> 3);
  bx = nf % gx;
  by = nf / gx;
}

// ---------------- fused fp32 -> bf16 convert: x + 4 weights, ONE dispatch ------
__global__ void cvt_all(const float* __restrict__ x,
                        const float* __restrict__ w0, const float* __restrict__ w1,
                        const float* __restrict__ w2, const float* __restrict__ w3,
                        bf16_t* __restrict__ dx, bf16_t* __restrict__ dw,
                        int nx8, int nw8) {
  const int i = blockIdx.x * blockDim.x + threadIdx.x;
  const float* s;
  bf16_t* d;
  int j;
  if (i < nx8) {
    s = x; d = dx; j = i;
  } else {
    const int k = i - nx8;
    const int seg = k / nw8;
    j = k - seg * nw8;
    s = (seg == 0) ? w0 : (seg == 1) ? w1 : (seg == 2) ? w2 : w3;
    d = dw + (size_t)seg * DM * DM;
  }
  const float4* sp = reinterpret_cast<const float4*>(s);
  float4 a = sp[2 * j], b = sp[2 * j + 1];
  u16x8 o;
  o[0] = f2bf_bits(a.x); o[1] = f2bf_bits(a.y); o[2] = f2bf_bits(a.z); o[3] = f2bf_bits(a.w);
  o[4] = f2bf_bits(b.x); o[5] = f2bf_bits(b.y); o[6] = f2bf_bits(b.z); o[7] = f2bf_bits(b.w);
  reinterpret_cast<u16x8*>(d)[j] = o;
}

// ---------------- gemm256: 256x256 tile, per-wave 128x64 (Q/K projections) ----
__global__ __launch_bounds__(512, 1) void gemm256(
    const bf16_t* __restrict__ A, const bf16_t* __restrict__ B,
    bf16_t* __restrict__ Cq, bf16_t* __restrict__ Ck) {
  __shared__ bf16_t Asm[3][256 * 64];   // 96 KB
  __shared__ bf16_t Bsm[2][256 * 64];   // 64 KB
  const int tid = threadIdx.x;
  const int l = tid & 63, w = tid >> 6;
  const int wm = w >> 2, wn = w & 3;        // 2M x 4N
  int bx, by; xcd_swz(bx, by);
  const int m0 = by * 256, n0 = bx * 256;
  const int NT = DM / 64;   // 32

  auto SA = [&](int t, int buf, int s) {          // s = 0..3 (A: 256 rows)
    const int rowbase = s * 64 + w * 8;           // wave-uniform
    const int row = rowbase + (l >> 3);
    const int ug = (l & 7) ^ (row & 7);
    const int tc = (t < NT) ? t : 0;              // dummy clamp (keeps vmcnt uniform)
    gll16(A + (size_t)(m0 + row) * DM + tc * 64 + ug * 8,
          (char*)Asm[buf] + rowbase * 128);
  };
  auto SB = [&](int t, int buf, int s) {          // s = 0..3 (B: 256 rows)
    const int rowbase = s * 64 + w * 8;
    const int row = rowbase + (l >> 3);
    const int ug = (l & 7) ^ (row & 7);
    const int tc = (t < NT) ? t : 0;
    gll16(B + (size_t)(n0 + row) * DM + tc * 64 + ug * 8,
          (char*)Bsm[buf] + rowbase * 128);
  };

  f32x4 acc[8][4] = {};

  // Prologue: A(0), B(0), A(1)  (queue: A0[4], B0[4], A1[4])
#pragma unroll
  for (int s = 0; s < 4; ++s) SA(0, 0, s);
#pragma unroll
  for (int s = 0; s < 4; ++s) SB(0, 0, s);
#pragma unroll
  for (int s = 0; s < 4; ++s) SA(1, 1, s);
  asm volatile("s_waitcnt vmcnt(4)" ::: "memory");   // A0,B0 complete; A1 floats
  __builtin_amdgcn_s_barrier();
  __builtin_amdgcn_sched_barrier(0);

  for (int j = 0; j < NT; ++j) {
    const int bjA = j % 3, bjB = j & 1;
    const int bsA = (j + 2) % 3, bsB = (j + 1) & 1;
    const char* Ab_ = (const char*)Asm[bjA];
    const char* Bb_ = (const char*)Bsm[bjB];

    // ---- sub-phase kh=0: 12 ds_read | stage B(j+1) | 32 MFMA ----
    {
      bf16x8 af[8], bfr[4];
#pragma unroll
      for (int mi = 0; mi < 8; ++mi) {
        const int row = wm * 128 + mi * 16 + (l & 15);
        const int u = (l >> 4) ^ (row & 7);
        af[mi] = *reinterpret_cast<const bf16x8*>(Ab_ + row * 128 + u * 16);
      }
#pragma unroll
      for (int ni = 0; ni < 4; ++ni) {
        const int row = wn * 64 + ni * 16 + (l & 15);
        const int u = (l >> 4) ^ (row & 7);
        bfr[ni] = *reinterpret_cast<const bf16x8*>(Bb_ + row * 128 + u * 16);
      }
      SB(j + 1, bsB, 0); SB(j + 1, bsB, 1); SB(j + 1, bsB, 2); SB(j + 1, bsB, 3);
      __builtin_amdgcn_sched_barrier(0);
      __builtin_amdgcn_s_setprio(1);
#pragma unroll
      for (int mi = 0; mi < 8; ++mi)
#pragma unroll
        for (int ni = 0; ni < 4; ++ni)
          acc[mi][ni] = __builtin_amdgcn_mfma_f32_16x16x32_bf16(
              af[mi], bfr[ni], acc[mi][ni], 0, 0, 0);
      __builtin_amdgcn_s_setprio(0);
    }

    // ---- sub-phase kh=1: 12 ds_read | stage A(j+2) | 32 MFMA ----
    {
      bf16x8 af[8], bfr[4];
#pragma unroll
      for (int mi = 0; mi < 8; ++mi) {
        const int row = wm * 128 + mi * 16 + (l & 15);
        const int u = (4 + (l >> 4)) ^ (row & 7);
        af[mi] = *reinterpret_cast<const bf16x8*>(Ab_ + row * 128 + u * 16);
      }
#pragma unroll
      for (int ni = 0; ni < 4; ++ni) {
        const int row = wn * 64 + ni * 16 + (l & 15);
        const int u = (4 + (l >> 4)) ^ (row & 7);
        bfr[ni] = *reinterpret_cast<const bf16x8*>(Bb_ + row * 128 + u * 16);
      }
      SA(j + 2, bsA, 0); SA(j + 2, bsA, 1); SA(j + 2, bsA, 2); SA(j + 2, bsA, 3);
      __builtin_amdgcn_sched_barrier(0);
      __builtin_amdgcn_s_setprio(1);
#pragma unroll
      for (int mi = 0; mi < 8; ++mi)
#pragma unroll
        for (int ni = 0; ni < 4; ++ni)
          acc[mi][ni] = __builtin_amdgcn_mfma_f32_16x16x32_bf16(
              af[mi], bfr[ni], acc[mi][ni], 0, 0, 0);
      __builtin_amdgcn_s_setprio(0);
    }

    // counted: A(j+1)+B(j+1) drained; only A(j+2)'s 4 loads remain
    asm volatile("s_waitcnt vmcnt(4)" ::: "memory");
    __builtin_amdgcn_s_barrier();
    __builtin_amdgcn_sched_barrier(0);
  }

  // ---- epilogue: n0 in [0,4096) -> proj 0 = Q, 1 = K ----
  bf16_t* C = (n0 >> 11) ? Ck : Cq;
  const int nc0 = n0 & (DM - 1);
#pragma unroll
  for (int mi = 0; mi < 8; ++mi) {
    const int row = m0 + wm * 128 + mi * 16 + ((l >> 4) << 2);
#pragma unroll
    for (int ni = 0; ni < 4; ++ni) {
      const int col = nc0 + wn * 64 + ni * 16 + (l & 15);
#pragma unroll
      for (int r = 0; r < 4; ++r)
        C[(size_t)(row + r) * DM + col] = f2bf(acc[mi][ni][r]);
    }
  }
}

// ---------------- 3-buffer counted-vmcnt GEMM (round-8 config, proven) --------
// OUTM: 1 = fp32 row-major to Cq (AO).  2 = V-only: per-head V^T to Cv.
template <int OUTM>
__global__ __launch_bounds__(512, 1) void gemm_3buf(
    const bf16_t* __restrict__ A, const bf16_t* __restrict__ B,
    void* __restrict__ Cq, void* __restrict__ Cv) {
  __shared__ bf16_t Asm[3][256 * 64];   // 96 KB
  __shared__ bf16_t Bsm[3][128 * 64];   // 48 KB
  const int tid = threadIdx.x;
  const int l = tid & 63, w = tid >> 6;
  const int wm = w >> 1, wn = w & 1;
  int bx, by; xcd_swz(bx, by);
  const int m0 = by * 256, n0 = bx * 128;
  const int NT = DM / 64;   // 32

  auto SA = [&](int t, int buf, int s) {          // s = 0..3 (A: 256 rows)
    const int rowbase = s * 64 + w * 8;           // wave-uniform
    const int row = rowbase + (l >> 3);
    const int ug = (l & 7) ^ (row & 7);
    const int tc = (t < NT) ? t : 0;              // dummy clamp (keeps vmcnt uniform)
    gll16(A + (size_t)(m0 + row) * DM + tc * 64 + ug * 8,
          (char*)Asm[buf] + rowbase * 128);
  };
  auto SB = [&](int t, int buf, int s) {          // s = 0..1 (B: 128 rows)
    const int rowbase = s * 64 + w * 8;
    const int row = rowbase + (l >> 3);
    const int ug = (l & 7) ^ (row & 7);
    const int tc = (t < NT) ? t : 0;
    gll16(B + (size_t)(n0 + row) * DM + tc * 64 + ug * 8,
          (char*)Bsm[buf] + rowbase * 128);
  };

  f32x4 acc[4][4] = {};

  // Prologue: stage tiles 0 and 1 (6 loads each).
#pragma unroll
  for (int s = 0; s < 4; ++s) SA(0, 0, s);
  SB(0, 0, 0); SB(0, 0, 1);
#pragma unroll
  for (int s = 0; s < 4; ++s) SA(1, 1, s);
  SB(1, 1, 0); SB(1, 1, 1);
  asm volatile("s_waitcnt vmcnt(6)" ::: "memory");   // tile 0 complete
  __builtin_amdgcn_s_barrier();
  __builtin_amdgcn_sched_barrier(0);

  for (int j = 0; j < NT; ++j) {
    const int bj = j % 3, bs = (j + 2) % 3;
    const char* Ab_ = (const char*)Asm[bj];
    const char* Bb_ = (const char*)Bsm[bj];
    bf16x8 af[4][2], bfr[4][2];

    // ---- full-tile ds_read burst (16 x b128, swizzled) ----
#pragma unroll
    for (int mi = 0; mi < 4; ++mi)
#pragma unroll
      for (int kh = 0; kh < 2; ++kh) {
        const int row = wm * 64 + mi * 16 + (l & 15);
        const int u = (kh * 4 + (l >> 4)) ^ (row & 7);
        af[mi][kh] = *reinterpret_cast<const bf16x8*>(Ab_ + row * 128 + u * 16);
      }
#pragma unroll
    for (int ni = 0; ni < 4; ++ni)
#pragma unroll
      for (int kh = 0; kh < 2; ++kh) {
        const int row = wn * 64 + ni * 16 + (l & 15);
        const int u = (kh * 4 + (l >> 4)) ^ (row & 7);
        bfr[ni][kh] = *reinterpret_cast<const bf16x8*>(Bb_ + row * 128 + u * 16);
      }

    // ---- stage tile j+2 (6 x gll16) ----
    SA(j + 2, bs, 0); SA(j + 2, bs, 1); SA(j + 2, bs, 2); SA(j + 2, bs, 3);
    SB(j + 2, bs, 0); SB(j + 2, bs, 1);
    __builtin_amdgcn_sched_barrier(0);   // pin MFMAs below the stage-issues

    // ---- 32 MFMA; kh-outer => 16 independent chains per cluster ----
    __builtin_amdgcn_s_setprio(1);
#pragma unroll
    for (int kh = 0; kh < 2; ++kh)
#pragma unroll
      for (int mi = 0; mi < 4; ++mi)
#pragma unroll
        for (int ni = 0; ni < 4; ++ni)
          acc[mi][ni] = __builtin_amdgcn_mfma_f32_16x16x32_bf16(
              af[mi][kh], bfr[ni][kh], acc[mi][ni], 0, 0, 0);
    __builtin_amdgcn_s_setprio(0);

    // counted: only tile j+2's 6 loads may remain in flight -> tile j+1 ready
    asm volatile("s_waitcnt vmcnt(6)" ::: "memory");
    __builtin_amdgcn_s_barrier();
    __builtin_amdgcn_sched_barrier(0);
  }

  // ---- epilogue ----
  if constexpr (OUTM == 2) {
    bf16_t* VT = (bf16_t*)Cv;
#pragma unroll
    for (int mi = 0; mi < 4; ++mi) {
      const int row = m0 + wm * 64 + mi * 16 + ((l >> 4) << 2);
      const int bb = row >> 11, tt = row & (TSEQ - 1);
#pragma unroll
      for (int ni = 0; ni < 4; ++ni) {
        const int col = n0 + wn * 64 + ni * 16 + (l & 15);
        const int hh = col >> 7, dd = col & (HD - 1);
        bf16x4 pk;
#pragma unroll
        for (int r = 0; r < 4; ++r) pk[r] = f2bf(acc[mi][ni][r]);
        *reinterpret_cast<bf16x4*>(VT + (((size_t)bb * NH + hh) * HD + dd) * TSEQ + tt) = pk;
      }
    }
  } else {
    float* C = (float*)Cq;
#pragma unroll
    for (int mi = 0; mi < 4; ++mi) {
      const int row = m0 + wm * 64 + mi * 16 + ((l >> 4) << 2);
#pragma unroll
      for (int ni = 0; ni < 4; ++ni) {
        const int col = n0 + wn * 64 + ni * 16 + (l & 15);
#pragma unroll
        for (int r = 0; r < 4; ++r)
          C[(size_t)(row + r) * DM + col] = acc[mi][ni][r];
      }
    }
  }
}

// ---------------- causal flash attention v6: kv-split wave pairs -----------------
// grid: (8, B*H) = 256 blocks. Block: 512 thr = 8 waves = 4 q-subblocks x 2 kv-halves.
// Block i runs q-tile i then q-tile 15-i (paired: 34 k-tiles each).
#define LDS_TOT 75776
__global__ __launch_bounds__(512, 2) void flash_attn(
    const bf16_t* __restrict__ Q, const bf16_t* __restrict__ Kx,
    const bf16_t* __restrict__ VT, bf16_t* __restrict__ O) {
  __shared__ __align__(16) char Lds[LDS_TOT];
  // staging (during loop): Ks[2] @0 (2x16 KB), Vs[2] @32768 (2x16 KB)
  // merge (after loop):   accbuf @0 (64 KB), ml @65536 (4 KB), ml2 @69632 (6 KB)

  const int tid = threadIdx.x;
  const int l = tid & 63, w = tid >> 6;
  const int hi = l >> 5, ln31 = l & 31;
  const int qw = w >> 1, kw = w & 1;
  int bix, bh; xcd_swz(bix, bh);        // blocks sharing bh (same K/V) -> same XCD
  const int b = bh >> 4, h = bh & 15;
  const size_t base   = ((size_t)b * TSEQ) * DM + (size_t)h * HD;   // Q/K/O
  const size_t vtbase = ((size_t)b * NH + h) * HD * (size_t)TSEQ;   // V^T
  const float cc = 0.12752775f;  // (1/sqrt(128)) * log2(e)

  auto run_qtile = [&](int qb) {
    const int wq0 = qb * 128 + qw * 32;
    const int nt = 2 * qb + 2;

    // Q as B-operand: lane holds col q = ln31, k(d) = m*16 + hi*8 + j
    bf16x8 qf[8];
    {
      const bf16_t* qp = Q + base + (size_t)(wq0 + ln31) * DM + hi * 8;
#pragma unroll
      for (int m = 0; m < 8; ++m)
        qf[m] = *reinterpret_cast<const bf16x8*>(qp + m * 16);
    }

    f32x16 acc[4] = {};   // O_half: row q=crow(r,hi), col d = n*32 + ln31
    float mrow = -1e30f, lrow = 0.f;

    auto STAGE = [&](int t, int buf) {
#pragma unroll
      for (int c = 0; c < 2; ++c) {
        const int chunk = w * 2 + c;                   // 0..15
        const int krow = chunk * 4 + (l >> 4);
        const int u = l & 15;
        const int ug = (u & 8) | ((u ^ krow) & 7);
        gll16(Kx + base + (size_t)(t * 64 + krow) * DM + ug * 8,
              Lds + buf * 16384 + chunk * 1024);
      }
#pragma unroll
      for (int c = 0; c < 2; ++c) {
        const int ci = w * 2 + c;                      // 0..15
        const int d = ci * 8 + (l >> 3);
        const int ug = (l & 7) ^ (l >> 3);
        gll16(VT + vtbase + (size_t)d * TSEQ + t * 64 + ug * 8,
              Lds + 32768 + buf * 16384 + ci * 1024);
      }
    };

    STAGE(0, 0);
    __syncthreads();
    int cur = 0;

    for (int t = 0; t < nt; ++t) {
      if (t + 1 < nt) STAGE(t + 1, cur ^ 1);

      const bool active = (t * 64 + kw * 32 <= wq0 + 31);
      if (active) {
        // ---- S^T_half = K_half Q^T : 8 MFMA ----
        f32x16 s = {};
        const char* Kb_ = Lds + cur * 16384;
        const int kvr = kw * 32 + ln31;
#pragma unroll
        for (int m = 0; m < 8; ++m) {
          const int u = 2 * m + hi;
          const int uswz = (u & 8) | ((u ^ kvr) & 7);
          const bf16x8 kf = *reinterpret_cast<const bf16x8*>(Kb_ + kvr * 256 + uswz * 16);
          s = __builtin_amdgcn_mfma_f32_32x32x16_bf16(kf, qf[m], s, 0, 0, 0);
        }

        // ---- scale + causal mask (q = ln31, kv = t*64 + kw*32 + crow(r,hi)) ----
        float sv[16];
        const int qg = wq0 + ln31;
#pragma unroll
        for (int r = 0; r < 16; ++r) sv[r] = s[r] * cc;
        if (t * 64 + kw * 32 + 31 > wq0) {
#pragma unroll
          for (int r = 0; r < 16; ++r) {
            const int kvg = t * 64 + kw * 32 + (r & 3) + 8 * (r >> 2) + 4 * hi;
            if (kvg > qg) sv[r] = -3.0e38f;
          }
        }

        // ---- row max over this half (16 regs + cross-hi) ----
        float mt = sv[0];
#pragma unroll
        for (int r = 1; r < 16; ++r) mt = fmaxf(mt, sv[r]);
        mt = fmaxf(mt, __shfl_xor(mt, 32, 64));

        // T13 defer-max; redistribute scl q->crow via shfl
        if (__any(mt > mrow + 8.0f)) {
          const float mn = fmaxf(mrow, mt);
          const float scl = fast_exp2(mrow - mn);
          mrow = mn;
          lrow *= scl;
#pragma unroll
          for (int r = 0; r < 16; ++r) {
            const float sr = __shfl(scl, (r & 3) + 8 * (r >> 2) + 4 * hi, 64);
            acc[0][r] *= sr; acc[1][r] *= sr; acc[2][r] *= sr; acc[3][r] *= sr;
          }
        }

        // ---- P = exp2(S - m), row sum ----
        float rs = 0.f;
#pragma unroll
        for (int r = 0; r < 16; ++r) {
          const float p = fast_exp2(sv[r] - mrow);
          sv[r] = p;
          rs += p;
        }
        rs += __shfl_xor(rs, 32, 64);
        lrow += rs;

        // ---- cvt_pk + permlane32_swap: 2 PV A-frags (kv-slots kw*2, kw*2+1) ----
        u32 frag[2][4];
#pragma unroll
        for (int f = 0; f < 2; ++f) {
          const float* p = &sv[f * 8];
          u32 a1 = cvtpk(p[0], p[1]);
          u32 b1 = cvtpk(p[4], p[5]);
          pl32swap(a1, b1);
          u32 a2 = cvtpk(p[2], p[3]);
          u32 b2 = cvtpk(p[6], p[7]);
          pl32swap(a2, b2);
          frag[f][0] = a1; frag[f][1] = a2; frag[f][2] = b1; frag[f][3] = b2;
        }

        // ---- O_half += P_half V_half : 2 kv-slots x 4 d-tiles ----
        const char* Vb_ = Lds + 32768 + cur * 16384;
#pragma unroll
        for (int f = 0; f < 2; ++f) {
          const bf16x8 pf = __builtin_bit_cast(bf16x8, *reinterpret_cast<u32(*)[4]>(frag[f]));
#pragma unroll
          for (int n = 0; n < 4; ++n) {
            const int d = n * 32 + ln31;
            const int u = (kw * 2 + f) * 2 + hi;
            const int uswz = u ^ (d & 7);
            const bf16x8 vf = *reinterpret_cast<const bf16x8*>(Vb_ + d * 128 + uswz * 16);
            acc[n] = __builtin_amdgcn_mfma_f32_32x32x16_bf16(pf, vf, acc[n], 0, 0, 0);
          }
        }
      }
      __syncthreads();
      cur ^= 1;
    }

    // ---- kv-pair merge + store (split by d-halves) ----
    {
      // 1) write my NON-finalized accs: kw=0 writes acc[2],acc[3]; kw=1 acc[0],acc[1]
      float* accb = (float*)(Lds + qw * 16384 + kw * 8192);
      const int nb = (kw == 0) ? 2 : 0;
#pragma unroll
      for (int np = 0; np < 2; ++np) {
        float* dst = accb + np * 1024;
#pragma unroll
        for (int r = 0; r < 16; ++r) {
          const int row = (r & 3) + 8 * (r >> 2) + 4 * hi;
          dst[row * 32 + ln31] = acc[nb + np][r];
        }
      }
      float* mlp = (float*)(Lds + 65536 + qw * 1024 + kw * 512);
      if (hi == 0) { mlp[ln31] = mrow; mlp[32 + ln31] = lrow; }
      __syncthreads();

      // 2) merge scalars at lane = q
      const float* mlo = (float*)(Lds + 65536 + qw * 1024 + (kw ^ 1) * 512);
      const float mo = mlo[ln31], lo = mlo[32 + ln31];
      const float mm = fmaxf(mrow, mo);
      const float as = fast_exp2(mrow - mm);
      const float ao = fast_exp2(mo - mm);
      const float rln = fast_rcp(lrow * as + lo * ao);
      float* ml2p = (float*)(Lds + 69632 + qw * 1536 + kw * 768);
      if (hi == 0) { ml2p[ln31] = as; ml2p[32 + ln31] = ao; ml2p[64 + ln31] = rln; }
      __syncthreads();

      // 3) finalize my d-half: kw=0 -> d 0..63 (acc[0],acc[1]), kw=1 -> d 64..127
      const float* accoth = (float*)(Lds + qw * 16384 + (kw ^ 1) * 8192);
      const int nf = (kw == 0) ? 0 : 2;
#pragma unroll
      for (int r = 0; r < 16; ++r) {
        const int row = (r & 3) + 8 * (r >> 2) + 4 * hi;
        const float asr = ml2p[row];
        const float aor = ml2p[32 + row];
        const float rlr = ml2p[64 + row];
        const int q = wq0 + row;
        bf16_t* op = O + base + (size_t)q * DM + ln31;
#pragma unroll
        for (int np = 0; np < 2; ++np) {
          const float vo = (acc[nf + np][r] * asr + accoth[np * 1024 + row * 32 + ln31] * aor) * rlr;
          op[(kw * 2 + np) * 32] = f2bf(vo);
        }
      }
      __syncthreads();   // LDS safe for next leg's staging
    }
  };

  const int i = bix;                      // 0..7 (post-swizzle)
  run_qtile(i);                           // short leg: 2i+2 k-tiles
  run_qtile((int)(TSEQ / 128) - 1 - i);   // long leg: 32-2i k-tiles (total 34)
}

// ---------------- launch ----------------
extern "C" void kernel_launch(void* const* d_in, const int* in_sizes, int n_in,
                              void* d_out, int out_size, void* d_ws, size_t ws_size,
                              hipStream_t stream) {
  (void)in_sizes; (void)n_in; (void)out_size; (void)ws_size;
  const float* x  = (const float*)d_in[0];
  const float* wq = (const float*)d_in[1];
  const float* wk = (const float*)d_in[2];
  const float* wv = (const float*)d_in[3];
  const float* wo = (const float*)d_in[4];
  float* out = (float*)d_out;

  const size_t nx = (size_t)MROWS * DM;  // 8388608
  const size_t nw = (size_t)DM * DM;     // 4194304
  bf16_t* xb  = (bf16_t*)d_ws;
  bf16_t* wqb = xb + nx;                 // wq/wk/wv/wo contiguous bf16
  bf16_t* wvb = wqb + 2 * nw;
  bf16_t* wob = wqb + 3 * nw;
  bf16_t* Qb  = wqb + 4 * nw;
  bf16_t* Kb  = Qb + nx;
  bf16_t* Vtb = Kb + nx;   // V^T [B][H][d][t]
  bf16_t* Ab  = Vtb + nx;

  const int nx8 = (int)(nx / 8);         // 1048576
  const int nw8 = (int)(nw / 8);         // 524288
  const int ntot = nx8 + 4 * nw8;        // 3145728
  cvt_all<<<ntot / 256, 256, 0, stream>>>(x, wq, wk, wv, wo, xb, wqb, nx8, nw8);

  // Q,K projections: 256x256 tiles, cols 0..4095 of fused [wq;wk]
  gemm256<<<dim3(2 * DM / 256, MROWS / 256), 512, 0, stream>>>(xb, wqb, Qb, Kb);
  // V projection: proven 256x128 kernel, V^T epilogue
  gemm_3buf<2><<<dim3(DM / 128, MROWS / 256), 512, 0, stream>>>(
      xb, wvb, nullptr, Vtb);

  flash_attn<<<dim3(TSEQ / 128 / 2, BATCH * NH), 512, 0, stream>>>(Qb, Kb, Vtb, Ab);

  gemm_3buf<1><<<dim3(DM / 128, MROWS / 256), 512, 0, stream>>>(
      Ab, wob, out, nullptr);
}